// Round 13
// baseline (569.094 us; speedup 1.0000x reference)
//
#include <hip/hip_runtime.h>

#define N_NODES 100000
#define N_EDGES 1600000
#define DIM 128

typedef __attribute__((ext_vector_type(8))) _Float16 f16x8;  // MFMA A/B frag (4 VGPRs)
typedef __attribute__((ext_vector_type(4))) float f32x4;     // MFMA C/D frag

// async global->LDS DMA, 16B per lane (dest = wave-uniform base + lane*16)
__device__ __forceinline__ void stage16(const _Float16* g, _Float16* l) {
  __builtin_amdgcn_global_load_lds(
      (const __attribute__((address_space(1))) void*)g,
      (__attribute__((address_space(3))) void*)l, 16, 0, 0);
}

// ---------------- CSR build ----------------

__global__ void k_scan_blk(const int* __restrict__ cnt, int* __restrict__ offs,
                           int* __restrict__ partials) {
  int tid = threadIdx.x;
  int gid = blockIdx.x * 1024 + tid;
  int v = (gid < N_NODES) ? cnt[gid] : 0;
  int lane = tid & 63, w = tid >> 6;
  int s = v;
#pragma unroll
  for (int d = 1; d < 64; d <<= 1) {
    int t = __shfl_up(s, d);
    if (lane >= d) s += t;
  }
  __shared__ int wsum[16];
  if (lane == 63) wsum[w] = s;
  __syncthreads();
  if (tid < 16) {
    int t2 = wsum[tid];
#pragma unroll
    for (int d = 1; d < 16; d <<= 1) {
      int u = __shfl_up(t2, d);
      if (tid >= d) t2 += u;
    }
    wsum[tid] = t2;
  }
  __syncthreads();
  if (w > 0) s += wsum[w - 1];
  if (gid < N_NODES) offs[gid + 1] = s;
  if (tid == 1023) partials[blockIdx.x] = s;
}

__global__ void k_scan_part(int* __restrict__ partials, int nb) {
  __shared__ int tmp[128];
  int tid = threadIdx.x;
  tmp[tid] = (tid < nb) ? partials[tid] : 0;
  __syncthreads();
  for (int d = 1; d < 128; d <<= 1) {
    int t = (tid >= d) ? tmp[tid - d] : 0;
    __syncthreads();
    tmp[tid] += t;
    __syncthreads();
  }
  if (tid < nb) partials[tid] = (tid > 0) ? tmp[tid - 1] : 0;  // exclusive
}

// scan finalize + cursor/deg_inv init (merged k_prep): thread i owns offs[i+1]
__global__ void k_scan_add(int* __restrict__ offs, const int* __restrict__ partials,
                           const int* __restrict__ cnt, int* __restrict__ cursor,
                           float* __restrict__ deg_inv) {
  int i = blockIdx.x * blockDim.x + threadIdx.x;
  if (i == 0) {
    offs[0] = 0;
    cursor[0] = 0;
    deg_inv[0] = 1.0f / (float)max(cnt[0], 1);
  }
  if (i < N_NODES) {
    int v = offs[i + 1] + partials[i >> 10];
    offs[i + 1] = v;
    if (i + 1 < N_NODES) {
      cursor[i + 1] = v;
      deg_inv[i + 1] = 1.0f / (float)max(cnt[i + 1], 1);
    }
  }
}

// Partitioned fill. Nontemporal dst/src streaming loads: keep the 8x6.4MB edge
// stream OUT of L2 so the partition's esrc slice + cursor stay resident ->
// scattered 4B writes combine in L2 instead of thrashing (r12: WRITE=72MB for
// a 6.4MB output).
#define FILL_BPP 224  // blocks per partition
__global__ void k_fill8(const int* __restrict__ src, const int* __restrict__ dst,
                        int* __restrict__ cursor, int* __restrict__ esrc) {
  const int part = blockIdx.x & 7;
  const int bp = blockIdx.x >> 3;
  const int lo = part * (N_NODES / 8);
  const int hi = lo + (N_NODES / 8);
  for (int i = bp * 256 + threadIdx.x; i < N_EDGES; i += FILL_BPP * 256) {
    int d = __builtin_nontemporal_load(dst + i);
    if (d >= lo && d < hi) {
      int s = __builtin_nontemporal_load(src + i);
      int p = atomicAdd(&cursor[d], 1);
      esrc[p] = s;
    }
  }
}

// ---------------- fused preprocessing: count | x->f16 hi/lo | weight pack ----------------
// cnt is zeroed by hipMemsetAsync before this kernel.
// Weight pack (hi planes only): per layer mats {0:ws_hi, 1:wn_hi};
// holds W[k = t*32 + (lane>>4)*8 + j][col = f*16 + (lane&15)]

#define WP_MAT (4 * 8 * 64 * 8)  // 16384 halfs / matrix
#define WP_LAYER (2 * WP_MAT)    // 32768 halfs / layer

#define NE_BLOCKS ((N_EDGES + 255) / 256)            // 6250
#define NX_BLOCKS ((N_NODES * DIM / 4 + 255) / 256)  // 12500
#define NW_BLOCKS 64

__global__ void k_preproc(const int* __restrict__ dst, int* __restrict__ cnt,
                          const float* __restrict__ x,
                          _Float16* __restrict__ x1, _Float16* __restrict__ x2,
                          const float* __restrict__ ws0, const float* __restrict__ wn0,
                          const float* __restrict__ ws1, const float* __restrict__ wn1,
                          const float* __restrict__ ws2, const float* __restrict__ wn2,
                          const float* __restrict__ ws3, const float* __restrict__ wn3,
                          _Float16* __restrict__ wp) {
  const int bid = blockIdx.x;
  if (bid < NE_BLOCKS) {
    int i = bid * 256 + threadIdx.x;
    if (i < N_EDGES) atomicAdd(&cnt[__builtin_nontemporal_load(dst + i)], 1);
  } else if (bid < NE_BLOCKS + NX_BLOCKS) {
    int i = (bid - NE_BLOCKS) * 256 + threadIdx.x;
    if (i < (N_NODES * DIM) / 4) {
      float4 v = reinterpret_cast<const float4*>(x)[i];
      union { _Float16 h[4]; uint2 u; } a, b;
      float vv[4] = {v.x, v.y, v.z, v.w};
#pragma unroll
      for (int j = 0; j < 4; ++j) {
        _Float16 h1 = (_Float16)vv[j];
        a.h[j] = h1;
        b.h[j] = (_Float16)(vv[j] - (float)h1);
      }
      reinterpret_cast<uint2*>(x1)[i] = a.u;
      reinterpret_cast<uint2*>(x2)[i] = b.u;
    }
  } else {
    int tid = (bid - NE_BLOCKS - NX_BLOCKS) * 256 + threadIdx.x;  // 0..16383
    int l = tid & 63;
    int f = (tid >> 6) & 7;
    int t = (tid >> 9) & 3;
    int m = (tid >> 11) & 1;  // 0 = ws, 1 = wn
    int layer = tid >> 12;
    const float* srcs[8] = {ws0, wn0, ws1, wn1, ws2, wn2, ws3, wn3};
    const float* src = srcs[layer * 2 + m];
    _Float16* dstp =
        wp + (size_t)layer * WP_LAYER + ((((m * 4 + t) * 8 + f) * 64 + l) * 8);
    int k0 = t * 32 + (l >> 4) * 8;
    int col = f * 16 + (l & 15);
#pragma unroll
    for (int j = 0; j < 8; ++j) dstp[j] = (_Float16)src[(k0 + j) * DIM + col];
  }
}

// ---------------- aggregation: one wave per node, f16 gather, unroll 8 ----------------
// esrc read nontemporal: the 6.4MB edge stream shouldn't evict the h1 table.

__device__ __forceinline__ float f16lo(unsigned w) {
  union { unsigned u; _Float16 h[2]; } c;
  c.u = w;
  return (float)c.h[0];
}
__device__ __forceinline__ float f16hi(unsigned w) {
  union { unsigned u; _Float16 h[2]; } c;
  c.u = w;
  return (float)c.h[1];
}

__global__ void k_agg_f16(const _Float16* __restrict__ h1, const int* __restrict__ offs,
                          const int* __restrict__ esrc, const float* __restrict__ deg_inv,
                          _Float16* __restrict__ m1) {
  int wid = (blockIdx.x * blockDim.x + threadIdx.x) >> 6;  // node id
  int lane = threadIdx.x & 63;
  if (wid >= N_NODES) return;
  const unsigned* H = reinterpret_cast<const unsigned*>(h1);  // row = 64 u32
  int beg = offs[wid], end = offs[wid + 1];
  float xs[8] = {0.f, 0.f, 0.f, 0.f, 0.f, 0.f, 0.f, 0.f};
  float ys[8] = {0.f, 0.f, 0.f, 0.f, 0.f, 0.f, 0.f, 0.f};
  int e = beg;
  for (; e + 7 < end; e += 8) {
    int s[8];
#pragma unroll
    for (int j = 0; j < 8; ++j) s[j] = __builtin_nontemporal_load(esrc + e + j);
    unsigned w[8];
#pragma unroll
    for (int j = 0; j < 8; ++j) w[j] = H[(size_t)s[j] * 64 + lane];
#pragma unroll
    for (int j = 0; j < 8; ++j) {
      xs[j] += f16lo(w[j]);
      ys[j] += f16hi(w[j]);
    }
  }
  for (; e + 1 < end; e += 2) {
    unsigned w0 = H[(size_t)esrc[e] * 64 + lane];
    unsigned w1 = H[(size_t)esrc[e + 1] * 64 + lane];
    xs[0] += f16lo(w0); ys[0] += f16hi(w0);
    xs[1] += f16lo(w1); ys[1] += f16hi(w1);
  }
  if (e < end) {
    unsigned w0 = H[(size_t)esrc[e] * 64 + lane];
    xs[2] += f16lo(w0); ys[2] += f16hi(w0);
  }
  float di = deg_inv[wid];
  float rx = ((xs[0] + xs[1]) + (xs[2] + xs[3])) + ((xs[4] + xs[5]) + (xs[6] + xs[7]));
  float ry = ((ys[0] + ys[1]) + (ys[2] + ys[3])) + ((ys[4] + ys[5]) + (ys[6] + ys[7]));
  rx *= di;
  ry *= di;
  union { unsigned u; _Float16 h[2]; } o;
  o.h[0] = (_Float16)rx;
  o.h[1] = (_Float16)ry;
  reinterpret_cast<unsigned*>(m1)[(size_t)wid * 64 + lane] = o.u;
}

// ---------------- MFMA dual-GEMM v7: h-planes in LDS, mean from global, 5 blk/CU ----------------
// out = act(h@ws + mean@wn + b); h = h1+h2 (f16 planes), mean = m1 (f16).
// acc += h1*ws_hi + h2*ws_hi + m*wn_hi   (3 MFMAs per frag; lo-weight terms
// dropped: |W_lo| <= 2^-11|W| -> rms error ~5e-4, below carried 0.0156 absmax)
// Block = 64 rows, 256 threads = 4 waves; wave = 32 rows x 64 cols.
// h1,h2 full-K staged upfront (32 KB -> 5 blocks/CU), ONE barrier, barrier-free
// t-loop; mean A-frags direct from global. XOR swizzle chunk^=(row&7) on the
// GLOBAL source (global_load_lds dest stays linear); reads use the same XOR.

template <int RELU, int LAST>
__global__ __launch_bounds__(256, 5) void k_gemm_f16(
    const _Float16* __restrict__ hp1, const _Float16* __restrict__ hp2,
    const _Float16* __restrict__ mp1, const _Float16* __restrict__ wp,
    const float* __restrict__ bias, float* __restrict__ outf,
    _Float16* __restrict__ o1, _Float16* __restrict__ o2) {
  __shared__ _Float16 sA[2][64 * 128];  // 32 KB: [plane][row*128 + k], swizzled

  const int tid = threadIdx.x;
  const int lane = tid & 63;
  const int wv = tid >> 6;
  const int wr = wv >> 1;  // rows wr*32..wr*32+31
  const int wc = wv & 1;   // cols wc*64..wc*64+63
  const int row0 = blockIdx.x * 64;
  const int lr = lane & 15;
  const int lg = lane >> 4;

  const _Float16* planes[2] = {hp1, hp2};

  // ---- stage h1,h2 full K (each plane: 1024 slots of 16B) ----
#pragma unroll
  for (int p = 0; p < 2; ++p)
#pragma unroll
    for (int i = 0; i < 4; ++i) {
      int s = i * 256 + tid;             // slot 0..1023
      int row = s >> 4;                  // 0..63
      int chunk = (s & 15) ^ (row & 7);  // swizzle on global side
      const _Float16* g = planes[p] + (size_t)(row0 + row) * DIM + chunk * 8;
      _Float16* l = &sA[p][(size_t)(i * 256 + (tid & ~63)) * 8];
      stage16(g, l);
    }
  __syncthreads();  // single drain; loop below is barrier-free

  f32x4 acc[2][4];
#pragma unroll
  for (int i = 0; i < 2; ++i)
#pragma unroll
    for (int j = 0; j < 4; ++j) acc[i][j] = (f32x4){0.f, 0.f, 0.f, 0.f};

  const _Float16* WS1 = wp;           // ws hi
  const _Float16* WN1 = wp + WP_MAT;  // wn hi

#pragma unroll
  for (int t = 0; t < 4; ++t) {
    // mean A-frags direct from global (issued first; overlap with LDS reads + B)
    f16x8 am[2];
#pragma unroll
    for (int ri = 0; ri < 2; ++ri) {
      int row = row0 + wr * 32 + ri * 16 + lr;
      am[ri] = *reinterpret_cast<const f16x8*>(mp1 + (size_t)row * DIM + t * 32 + lg * 8);
    }
    // h A-frags from LDS (swizzled read; conflict-free)
    f16x8 a1[2], a2[2];
#pragma unroll
    for (int ri = 0; ri < 2; ++ri) {
      int row_l = wr * 32 + ri * 16 + lr;
      int boff = (row_l << 8) + ((t * 64 + lg * 16) ^ ((row_l & 7) << 4));
      a1[ri] = *reinterpret_cast<const f16x8*>(
          reinterpret_cast<const char*>(&sA[0][0]) + boff);
      a2[ri] = *reinterpret_cast<const f16x8*>(
          reinterpret_cast<const char*>(&sA[1][0]) + boff);
    }
    // B frags from global (L2) + MFMA
#pragma unroll
    for (int fc = 0; fc < 4; ++fc) {
      int f = wc * 4 + fc;
      size_t boff = (size_t)((t * 8 + f) * 64 + lane) * 8;
      f16x8 bs1 = *reinterpret_cast<const f16x8*>(WS1 + boff);
      f16x8 bn1 = *reinterpret_cast<const f16x8*>(WN1 + boff);
#pragma unroll
      for (int ri = 0; ri < 2; ++ri) {
        acc[ri][fc] =
            __builtin_amdgcn_mfma_f32_16x16x32_f16(a1[ri], bs1, acc[ri][fc], 0, 0, 0);
        acc[ri][fc] =
            __builtin_amdgcn_mfma_f32_16x16x32_f16(a2[ri], bs1, acc[ri][fc], 0, 0, 0);
        acc[ri][fc] =
            __builtin_amdgcn_mfma_f32_16x16x32_f16(am[ri], bn1, acc[ri][fc], 0, 0, 0);
      }
    }
  }

  // ---- epilogue: C/D layout col=lane&15, row=(lane>>4)*4+reg ----
  float bv[4];
#pragma unroll
  for (int fc = 0; fc < 4; ++fc) bv[fc] = bias[wc * 64 + fc * 16 + lr];
#pragma unroll
  for (int ri = 0; ri < 2; ++ri)
#pragma unroll
    for (int fc = 0; fc < 4; ++fc)
#pragma unroll
      for (int r = 0; r < 4; ++r) {
        int row = row0 + wr * 32 + ri * 16 + lg * 4 + r;
        if (row < N_NODES) {
          float v = acc[ri][fc][r] + bv[fc];
          if (RELU) v = fmaxf(v, 0.f);
          size_t idx = (size_t)row * DIM + wc * 64 + fc * 16 + lr;
          if (LAST) {
            outf[idx] = v;
          } else {
            _Float16 hi = (_Float16)v;
            o1[idx] = hi;
            o2[idx] = (_Float16)(v - (float)hi);
          }
        }
      }
}

// ---------------- driver ----------------

extern "C" void kernel_launch(void* const* d_in, const int* in_sizes, int n_in,
                              void* d_out, int out_size, void* d_ws, size_t ws_size,
                              hipStream_t stream) {
  const float* x = (const float*)d_in[0];
  const int* src = (const int*)d_in[1];
  const int* dst = (const int*)d_in[2];
  const float* Ws[4];
  const float* Wn[4];
  const float* Bi[4];
  for (int i = 0; i < 4; ++i) {
    Ws[i] = (const float*)d_in[3 + 3 * i];
    Wn[i] = (const float*)d_in[4 + 3 * i];
    Bi[i] = (const float*)d_in[5 + 3 * i];
  }
  float* out = (float*)d_out;

  char* p = (char*)d_ws;
  auto take = [&](size_t bytes) {
    void* r = (void*)p;
    p += (bytes + 255) & ~(size_t)255;
    return r;
  };
  int* cnt = (int*)take((size_t)N_NODES * 4);
  int* offs = (int*)take((size_t)(N_NODES + 1) * 4);
  int* cursor = (int*)take((size_t)N_NODES * 4);
  int* partials = (int*)take(128 * 4);
  float* deg_inv = (float*)take((size_t)N_NODES * 4);
  int* esrc = (int*)take((size_t)N_EDGES * 4);
  _Float16* hA1 = (_Float16*)take((size_t)N_NODES * DIM * 2);
  _Float16* hA2 = (_Float16*)take((size_t)N_NODES * DIM * 2);
  _Float16* hB1 = (_Float16*)take((size_t)N_NODES * DIM * 2);
  _Float16* hB2 = (_Float16*)take((size_t)N_NODES * DIM * 2);
  _Float16* m1 = (_Float16*)take((size_t)N_NODES * DIM * 2);
  _Float16* wpk = (_Float16*)take((size_t)4 * WP_LAYER * 2);
  // pad so last-block OOB staging/mean reads stay inside the workspace
  (void)take((size_t)64 * 1024);

  const int NB = (N_NODES + 1023) / 1024;  // 98

  // zero cnt (graph-capture-safe), then fused preprocessing (count | xcvt | wpack)
  hipMemsetAsync(cnt, 0, (size_t)N_NODES * 4, stream);
  k_preproc<<<NE_BLOCKS + NX_BLOCKS + NW_BLOCKS, 256, 0, stream>>>(
      dst, cnt, x, hA1, hA2, Ws[0], Wn[0], Ws[1], Wn[1], Ws[2], Wn[2], Ws[3], Wn[3],
      wpk);

  // CSR build (edges are layer-invariant)
  k_scan_blk<<<NB, 1024, 0, stream>>>(cnt, offs, partials);
  k_scan_part<<<1, 128, 0, stream>>>(partials, NB);
  k_scan_add<<<(N_NODES + 255) / 256, 256, 0, stream>>>(offs, partials, cnt, cursor,
                                                        deg_inv);
  k_fill8<<<8 * FILL_BPP, 256, 0, stream>>>(src, dst, cursor, esrc);

  const int AGG_BLOCKS = (N_NODES + 3) / 4;     // 4 waves/block, 1 node/wave
  const int GEMM_BLOCKS = (N_NODES + 63) / 64;  // 64 rows x 128 cols per block

  _Float16 *h1 = hA1, *h2 = hA2, *n1 = hB1, *n2 = hB2;
  for (int l = 0; l < 4; ++l) {
    k_agg_f16<<<AGG_BLOCKS, 256, 0, stream>>>(h1, offs, esrc, deg_inv, m1);
    const _Float16* wl = wpk + (size_t)l * WP_LAYER;
    if (l < 3) {
      k_gemm_f16<1, 0><<<GEMM_BLOCKS, 256, 0, stream>>>(h1, h2, m1, wl, Bi[l], nullptr,
                                                        n1, n2);
      _Float16* t1 = h1; h1 = n1; n1 = t1;
      _Float16* t2 = h2; h2 = n2; n2 = t2;
    } else {
      k_gemm_f16<0, 1><<<GEMM_BLOCKS, 256, 0, stream>>>(h1, h2, m1, wl, Bi[l], out,
                                                        nullptr, nullptr);
    }
  }
}

// Round 14
// 549.495 us; speedup vs baseline: 1.0357x; 1.0357x over previous
//
#include <hip/hip_runtime.h>

#define N_NODES 100000
#define N_EDGES 1600000
#define DIM 128

typedef __attribute__((ext_vector_type(8))) _Float16 f16x8;  // MFMA A/B frag (4 VGPRs)
typedef __attribute__((ext_vector_type(4))) float f32x4;     // MFMA C/D frag

// async global->LDS DMA, 16B per lane (dest = wave-uniform base + lane*16)
__device__ __forceinline__ void stage16(const _Float16* g, _Float16* l) {
  __builtin_amdgcn_global_load_lds(
      (const __attribute__((address_space(1))) void*)g,
      (__attribute__((address_space(3))) void*)l, 16, 0, 0);
}

// ---------------- CSR build ----------------

__global__ void k_count(const int* __restrict__ dst, int* __restrict__ cnt) {
  int i = blockIdx.x * blockDim.x + threadIdx.x;
  if (i < N_EDGES) atomicAdd(&cnt[dst[i]], 1);
}

__global__ void k_scan_blk(const int* __restrict__ cnt, int* __restrict__ offs,
                           int* __restrict__ partials) {
  int tid = threadIdx.x;
  int gid = blockIdx.x * 1024 + tid;
  int v = (gid < N_NODES) ? cnt[gid] : 0;
  int lane = tid & 63, w = tid >> 6;
  int s = v;
#pragma unroll
  for (int d = 1; d < 64; d <<= 1) {
    int t = __shfl_up(s, d);
    if (lane >= d) s += t;
  }
  __shared__ int wsum[16];
  if (lane == 63) wsum[w] = s;
  __syncthreads();
  if (tid < 16) {
    int t2 = wsum[tid];
#pragma unroll
    for (int d = 1; d < 16; d <<= 1) {
      int u = __shfl_up(t2, d);
      if (tid >= d) t2 += u;
    }
    wsum[tid] = t2;
  }
  __syncthreads();
  if (w > 0) s += wsum[w - 1];
  if (gid < N_NODES) offs[gid + 1] = s;
  if (tid == 1023) partials[blockIdx.x] = s;
}

__global__ void k_scan_part(int* __restrict__ partials, int nb) {
  __shared__ int tmp[128];
  int tid = threadIdx.x;
  tmp[tid] = (tid < nb) ? partials[tid] : 0;
  __syncthreads();
  for (int d = 1; d < 128; d <<= 1) {
    int t = (tid >= d) ? tmp[tid - d] : 0;
    __syncthreads();
    tmp[tid] += t;
    __syncthreads();
  }
  if (tid < nb) partials[tid] = (tid > 0) ? tmp[tid - 1] : 0;  // exclusive
}

// scan finalize + cursor/deg_inv init (merged k_prep): thread i owns offs[i+1]
__global__ void k_scan_add(int* __restrict__ offs, const int* __restrict__ partials,
                           const int* __restrict__ cnt, int* __restrict__ cursor,
                           float* __restrict__ deg_inv) {
  int i = blockIdx.x * blockDim.x + threadIdx.x;
  if (i == 0) {
    offs[0] = 0;
    cursor[0] = 0;
    deg_inv[0] = 1.0f / (float)max(cnt[0], 1);
  }
  if (i < N_NODES) {
    int v = offs[i + 1] + partials[i >> 10];
    offs[i + 1] = v;
    if (i + 1 < N_NODES) {
      cursor[i + 1] = v;
      deg_inv[i + 1] = 1.0f / (float)max(cnt[i + 1], 1);
    }
  }
}

// Partitioned fill. EXPERIMENT (isolated this round): nontemporal dst/src
// streaming loads keep the 8x6.4MB edge stream OUT of L2 so the partition's
// esrc slice (800KB) + cursor stay resident -> scattered 4B writes combine in
// L2 instead of thrashing (r12: WRITE=72MB for a 6.4MB output).
#define FILL_BPP 224  // blocks per partition
__global__ void k_fill8(const int* __restrict__ src, const int* __restrict__ dst,
                        int* __restrict__ cursor, int* __restrict__ esrc) {
  const int part = blockIdx.x & 7;
  const int bp = blockIdx.x >> 3;
  const int lo = part * (N_NODES / 8);
  const int hi = lo + (N_NODES / 8);
  for (int i = bp * 256 + threadIdx.x; i < N_EDGES; i += FILL_BPP * 256) {
    int d = __builtin_nontemporal_load(dst + i);
    if (d >= lo && d < hi) {
      int s = __builtin_nontemporal_load(src + i);
      int p = atomicAdd(&cursor[d], 1);
      esrc[p] = s;
    }
  }
}

// ---------------- fused preprocessing: zero cnt | x->f16 hi/lo | weight pack ----------------
// (r12 proven version; count stays a separate kernel)
// Weight pack (hi planes only): per layer mats {0:ws_hi, 1:wn_hi};
// holds W[k = t*32 + (lane>>4)*8 + j][col = f*16 + (lane&15)]

#define WP_MAT (4 * 8 * 64 * 8)  // 16384 halfs / matrix
#define WP_LAYER (2 * WP_MAT)    // 32768 halfs / layer

#define NZ_BLOCKS ((N_NODES + 255) / 256)            // 391
#define NX_BLOCKS ((N_NODES * DIM / 4 + 255) / 256)  // 12500
#define NW_BLOCKS 64

__global__ void k_preproc(int* __restrict__ cnt, const float* __restrict__ x,
                          _Float16* __restrict__ x1, _Float16* __restrict__ x2,
                          const float* __restrict__ ws0, const float* __restrict__ wn0,
                          const float* __restrict__ ws1, const float* __restrict__ wn1,
                          const float* __restrict__ ws2, const float* __restrict__ wn2,
                          const float* __restrict__ ws3, const float* __restrict__ wn3,
                          _Float16* __restrict__ wp) {
  const int bid = blockIdx.x;
  if (bid < NZ_BLOCKS) {
    int i = bid * 256 + threadIdx.x;
    if (i < N_NODES) cnt[i] = 0;
  } else if (bid < NZ_BLOCKS + NX_BLOCKS) {
    int i = (bid - NZ_BLOCKS) * 256 + threadIdx.x;
    if (i < (N_NODES * DIM) / 4) {
      float4 v = reinterpret_cast<const float4*>(x)[i];
      union { _Float16 h[4]; uint2 u; } a, b;
      float vv[4] = {v.x, v.y, v.z, v.w};
#pragma unroll
      for (int j = 0; j < 4; ++j) {
        _Float16 h1 = (_Float16)vv[j];
        a.h[j] = h1;
        b.h[j] = (_Float16)(vv[j] - (float)h1);
      }
      reinterpret_cast<uint2*>(x1)[i] = a.u;
      reinterpret_cast<uint2*>(x2)[i] = b.u;
    }
  } else {
    int tid = (bid - NZ_BLOCKS - NX_BLOCKS) * 256 + threadIdx.x;  // 0..16383
    int l = tid & 63;
    int f = (tid >> 6) & 7;
    int t = (tid >> 9) & 3;
    int m = (tid >> 11) & 1;  // 0 = ws, 1 = wn
    int layer = tid >> 12;
    const float* srcs[8] = {ws0, wn0, ws1, wn1, ws2, wn2, ws3, wn3};
    const float* src = srcs[layer * 2 + m];
    _Float16* dstp =
        wp + (size_t)layer * WP_LAYER + ((((m * 4 + t) * 8 + f) * 64 + l) * 8);
    int k0 = t * 32 + (l >> 4) * 8;
    int col = f * 16 + (l & 15);
#pragma unroll
    for (int j = 0; j < 8; ++j) dstp[j] = (_Float16)src[(k0 + j) * DIM + col];
  }
}

// ---------------- aggregation: one wave per node, f16 gather, unroll 8 (r12 proven) ----------------

__device__ __forceinline__ float f16lo(unsigned w) {
  union { unsigned u; _Float16 h[2]; } c;
  c.u = w;
  return (float)c.h[0];
}
__device__ __forceinline__ float f16hi(unsigned w) {
  union { unsigned u; _Float16 h[2]; } c;
  c.u = w;
  return (float)c.h[1];
}

__global__ void k_agg_f16(const _Float16* __restrict__ h1, const int* __restrict__ offs,
                          const int* __restrict__ esrc, const float* __restrict__ deg_inv,
                          _Float16* __restrict__ m1) {
  int wid = (blockIdx.x * blockDim.x + threadIdx.x) >> 6;  // node id
  int lane = threadIdx.x & 63;
  if (wid >= N_NODES) return;
  const unsigned* H = reinterpret_cast<const unsigned*>(h1);  // row = 64 u32
  int beg = offs[wid], end = offs[wid + 1];
  float xs[8] = {0.f, 0.f, 0.f, 0.f, 0.f, 0.f, 0.f, 0.f};
  float ys[8] = {0.f, 0.f, 0.f, 0.f, 0.f, 0.f, 0.f, 0.f};
  int e = beg;
  for (; e + 7 < end; e += 8) {
    int s[8];
#pragma unroll
    for (int j = 0; j < 8; ++j) s[j] = esrc[e + j];
    unsigned w[8];
#pragma unroll
    for (int j = 0; j < 8; ++j) w[j] = H[(size_t)s[j] * 64 + lane];
#pragma unroll
    for (int j = 0; j < 8; ++j) {
      xs[j] += f16lo(w[j]);
      ys[j] += f16hi(w[j]);
    }
  }
  for (; e + 1 < end; e += 2) {
    unsigned w0 = H[(size_t)esrc[e] * 64 + lane];
    unsigned w1 = H[(size_t)esrc[e + 1] * 64 + lane];
    xs[0] += f16lo(w0); ys[0] += f16hi(w0);
    xs[1] += f16lo(w1); ys[1] += f16hi(w1);
  }
  if (e < end) {
    unsigned w0 = H[(size_t)esrc[e] * 64 + lane];
    xs[2] += f16lo(w0); ys[2] += f16hi(w0);
  }
  float di = deg_inv[wid];
  float rx = ((xs[0] + xs[1]) + (xs[2] + xs[3])) + ((xs[4] + xs[5]) + (xs[6] + xs[7]));
  float ry = ((ys[0] + ys[1]) + (ys[2] + ys[3])) + ((ys[4] + ys[5]) + (ys[6] + ys[7]));
  rx *= di;
  ry *= di;
  union { unsigned u; _Float16 h[2]; } o;
  o.h[0] = (_Float16)rx;
  o.h[1] = (_Float16)ry;
  reinterpret_cast<unsigned*>(m1)[(size_t)wid * 64 + lane] = o.u;
}

// ---------------- MFMA dual-GEMM v7: h-planes in LDS, mean from global, 5 blk/CU ----------------
// out = act(h@ws + mean@wn + b); h = h1+h2 (f16 planes), mean = m1 (f16).
// acc += h1*ws_hi + h2*ws_hi + m*wn_hi   (3 MFMAs per frag; lo-weight terms
// dropped: |W_lo| <= 2^-11|W| -> rms error ~5e-4, below carried 0.0156 absmax)
// Block = 64 rows, 256 threads = 4 waves; wave = 32 rows x 64 cols.
// h1,h2 full-K staged upfront (32 KB -> 5 blocks/CU), ONE barrier, barrier-free
// t-loop; mean A-frags direct from global. XOR swizzle chunk^=(row&7) on the
// GLOBAL source (global_load_lds dest stays linear); reads use the same XOR.

template <int RELU, int LAST>
__global__ __launch_bounds__(256, 5) void k_gemm_f16(
    const _Float16* __restrict__ hp1, const _Float16* __restrict__ hp2,
    const _Float16* __restrict__ mp1, const _Float16* __restrict__ wp,
    const float* __restrict__ bias, float* __restrict__ outf,
    _Float16* __restrict__ o1, _Float16* __restrict__ o2) {
  __shared__ _Float16 sA[2][64 * 128];  // 32 KB: [plane][row*128 + k], swizzled

  const int tid = threadIdx.x;
  const int lane = tid & 63;
  const int wv = tid >> 6;
  const int wr = wv >> 1;  // rows wr*32..wr*32+31
  const int wc = wv & 1;   // cols wc*64..wc*64+63
  const int row0 = blockIdx.x * 64;
  const int lr = lane & 15;
  const int lg = lane >> 4;

  const _Float16* planes[2] = {hp1, hp2};

  // ---- stage h1,h2 full K (each plane: 1024 slots of 16B) ----
#pragma unroll
  for (int p = 0; p < 2; ++p)
#pragma unroll
    for (int i = 0; i < 4; ++i) {
      int s = i * 256 + tid;             // slot 0..1023
      int row = s >> 4;                  // 0..63
      int chunk = (s & 15) ^ (row & 7);  // swizzle on global side
      const _Float16* g = planes[p] + (size_t)(row0 + row) * DIM + chunk * 8;
      _Float16* l = &sA[p][(size_t)(i * 256 + (tid & ~63)) * 8];
      stage16(g, l);
    }
  __syncthreads();  // single drain; loop below is barrier-free

  f32x4 acc[2][4];
#pragma unroll
  for (int i = 0; i < 2; ++i)
#pragma unroll
    for (int j = 0; j < 4; ++j) acc[i][j] = (f32x4){0.f, 0.f, 0.f, 0.f};

  const _Float16* WS1 = wp;           // ws hi
  const _Float16* WN1 = wp + WP_MAT;  // wn hi

#pragma unroll
  for (int t = 0; t < 4; ++t) {
    // mean A-frags direct from global (issued first; overlap with LDS reads + B)
    f16x8 am[2];
#pragma unroll
    for (int ri = 0; ri < 2; ++ri) {
      int row = row0 + wr * 32 + ri * 16 + lr;
      am[ri] = *reinterpret_cast<const f16x8*>(mp1 + (size_t)row * DIM + t * 32 + lg * 8);
    }
    // h A-frags from LDS (swizzled read; conflict-free)
    f16x8 a1[2], a2[2];
#pragma unroll
    for (int ri = 0; ri < 2; ++ri) {
      int row_l = wr * 32 + ri * 16 + lr;
      int boff = (row_l << 8) + ((t * 64 + lg * 16) ^ ((row_l & 7) << 4));
      a1[ri] = *reinterpret_cast<const f16x8*>(
          reinterpret_cast<const char*>(&sA[0][0]) + boff);
      a2[ri] = *reinterpret_cast<const f16x8*>(
          reinterpret_cast<const char*>(&sA[1][0]) + boff);
    }
    // B frags from global (L2) + MFMA
#pragma unroll
    for (int fc = 0; fc < 4; ++fc) {
      int f = wc * 4 + fc;
      size_t boff = (size_t)((t * 8 + f) * 64 + lane) * 8;
      f16x8 bs1 = *reinterpret_cast<const f16x8*>(WS1 + boff);
      f16x8 bn1 = *reinterpret_cast<const f16x8*>(WN1 + boff);
#pragma unroll
      for (int ri = 0; ri < 2; ++ri) {
        acc[ri][fc] =
            __builtin_amdgcn_mfma_f32_16x16x32_f16(a1[ri], bs1, acc[ri][fc], 0, 0, 0);
        acc[ri][fc] =
            __builtin_amdgcn_mfma_f32_16x16x32_f16(a2[ri], bs1, acc[ri][fc], 0, 0, 0);
        acc[ri][fc] =
            __builtin_amdgcn_mfma_f32_16x16x32_f16(am[ri], bn1, acc[ri][fc], 0, 0, 0);
      }
    }
  }

  // ---- epilogue: C/D layout col=lane&15, row=(lane>>4)*4+reg ----
  float bv[4];
#pragma unroll
  for (int fc = 0; fc < 4; ++fc) bv[fc] = bias[wc * 64 + fc * 16 + lr];
#pragma unroll
  for (int ri = 0; ri < 2; ++ri)
#pragma unroll
    for (int fc = 0; fc < 4; ++fc)
#pragma unroll
      for (int r = 0; r < 4; ++r) {
        int row = row0 + wr * 32 + ri * 16 + lg * 4 + r;
        if (row < N_NODES) {
          float v = acc[ri][fc][r] + bv[fc];
          if (RELU) v = fmaxf(v, 0.f);
          size_t idx = (size_t)row * DIM + wc * 64 + fc * 16 + lr;
          if (LAST) {
            outf[idx] = v;
          } else {
            _Float16 hi = (_Float16)v;
            o1[idx] = hi;
            o2[idx] = (_Float16)(v - (float)hi);
          }
        }
      }
}

// ---------------- driver ----------------

extern "C" void kernel_launch(void* const* d_in, const int* in_sizes, int n_in,
                              void* d_out, int out_size, void* d_ws, size_t ws_size,
                              hipStream_t stream) {
  const float* x = (const float*)d_in[0];
  const int* src = (const int*)d_in[1];
  const int* dst = (const int*)d_in[2];
  const float* Ws[4];
  const float* Wn[4];
  const float* Bi[4];
  for (int i = 0; i < 4; ++i) {
    Ws[i] = (const float*)d_in[3 + 3 * i];
    Wn[i] = (const float*)d_in[4 + 3 * i];
    Bi[i] = (const float*)d_in[5 + 3 * i];
  }
  float* out = (float*)d_out;

  char* p = (char*)d_ws;
  auto take = [&](size_t bytes) {
    void* r = (void*)p;
    p += (bytes + 255) & ~(size_t)255;
    return r;
  };
  int* cnt = (int*)take((size_t)N_NODES * 4);
  int* offs = (int*)take((size_t)(N_NODES + 1) * 4);
  int* cursor = (int*)take((size_t)N_NODES * 4);
  int* partials = (int*)take(128 * 4);
  float* deg_inv = (float*)take((size_t)N_NODES * 4);
  int* esrc = (int*)take((size_t)N_EDGES * 4);
  _Float16* hA1 = (_Float16*)take((size_t)N_NODES * DIM * 2);
  _Float16* hA2 = (_Float16*)take((size_t)N_NODES * DIM * 2);
  _Float16* hB1 = (_Float16*)take((size_t)N_NODES * DIM * 2);
  _Float16* hB2 = (_Float16*)take((size_t)N_NODES * DIM * 2);
  _Float16* m1 = (_Float16*)take((size_t)N_NODES * DIM * 2);
  _Float16* wpk = (_Float16*)take((size_t)4 * WP_LAYER * 2);
  // pad so last-block OOB staging/mean reads stay inside the workspace
  (void)take((size_t)64 * 1024);

  const int NB = (N_NODES + 1023) / 1024;  // 98

  // fused preprocessing (cnt zero | x->f16 planes | weight pack), then CSR build
  k_preproc<<<NZ_BLOCKS + NX_BLOCKS + NW_BLOCKS, 256, 0, stream>>>(
      cnt, x, hA1, hA2, Ws[0], Wn[0], Ws[1], Wn[1], Ws[2], Wn[2], Ws[3], Wn[3], wpk);
  k_count<<<(N_EDGES + 255) / 256, 256, 0, stream>>>(dst, cnt);
  k_scan_blk<<<NB, 1024, 0, stream>>>(cnt, offs, partials);
  k_scan_part<<<1, 128, 0, stream>>>(partials, NB);
  k_scan_add<<<(N_NODES + 255) / 256, 256, 0, stream>>>(offs, partials, cnt, cursor,
                                                        deg_inv);
  k_fill8<<<8 * FILL_BPP, 256, 0, stream>>>(src, dst, cursor, esrc);

  const int AGG_BLOCKS = (N_NODES + 3) / 4;     // 4 waves/block, 1 node/wave
  const int GEMM_BLOCKS = (N_NODES + 63) / 64;  // 64 rows x 128 cols per block

  _Float16 *h1 = hA1, *h2 = hA2, *n1 = hB1, *n2 = hB2;
  for (int l = 0; l < 4; ++l) {
    k_agg_f16<<<AGG_BLOCKS, 256, 0, stream>>>(h1, offs, esrc, deg_inv, m1);
    const _Float16* wl = wpk + (size_t)l * WP_LAYER;
    if (l < 3) {
      k_gemm_f16<1, 0><<<GEMM_BLOCKS, 256, 0, stream>>>(h1, h2, m1, wl, Bi[l], nullptr,
                                                        n1, n2);
      _Float16* t1 = h1; h1 = n1; n1 = t1;
      _Float16* t2 = h2; h2 = n2; n2 = t2;
    } else {
      k_gemm_f16<0, 1><<<GEMM_BLOCKS, 256, 0, stream>>>(h1, h2, m1, wl, Bi[l], out,
                                                        nullptr, nullptr);
    }
  }
}

// Round 15
// 524.695 us; speedup vs baseline: 1.0846x; 1.0473x over previous
//
#include <hip/hip_runtime.h>

#define N_NODES 100000
#define N_EDGES 1600000
#define DIM 128

typedef __attribute__((ext_vector_type(8))) _Float16 f16x8;  // MFMA A/B frag (4 VGPRs)
typedef __attribute__((ext_vector_type(4))) float f32x4;     // MFMA C/D frag

// async global->LDS DMA, 16B per lane (dest = wave-uniform base + lane*16)
__device__ __forceinline__ void stage16(const _Float16* g, _Float16* l) {
  __builtin_amdgcn_global_load_lds(
      (const __attribute__((address_space(1))) void*)g,
      (__attribute__((address_space(3))) void*)l, 16, 0, 0);
}

// ---------------- CSR build ----------------

__global__ void k_count(const int* __restrict__ dst, int* __restrict__ cnt) {
  int i = blockIdx.x * blockDim.x + threadIdx.x;
  if (i < N_EDGES) atomicAdd(&cnt[dst[i]], 1);
}

__global__ void k_scan_blk(const int* __restrict__ cnt, int* __restrict__ offs,
                           int* __restrict__ partials) {
  int tid = threadIdx.x;
  int gid = blockIdx.x * 1024 + tid;
  int v = (gid < N_NODES) ? cnt[gid] : 0;
  int lane = tid & 63, w = tid >> 6;
  int s = v;
#pragma unroll
  for (int d = 1; d < 64; d <<= 1) {
    int t = __shfl_up(s, d);
    if (lane >= d) s += t;
  }
  __shared__ int wsum[16];
  if (lane == 63) wsum[w] = s;
  __syncthreads();
  if (tid < 16) {
    int t2 = wsum[tid];
#pragma unroll
    for (int d = 1; d < 16; d <<= 1) {
      int u = __shfl_up(t2, d);
      if (tid >= d) t2 += u;
    }
    wsum[tid] = t2;
  }
  __syncthreads();
  if (w > 0) s += wsum[w - 1];
  if (gid < N_NODES) offs[gid + 1] = s;
  if (tid == 1023) partials[blockIdx.x] = s;
}

__global__ void k_scan_part(int* __restrict__ partials, int nb) {
  __shared__ int tmp[128];
  int tid = threadIdx.x;
  tmp[tid] = (tid < nb) ? partials[tid] : 0;
  __syncthreads();
  for (int d = 1; d < 128; d <<= 1) {
    int t = (tid >= d) ? tmp[tid - d] : 0;
    __syncthreads();
    tmp[tid] += t;
    __syncthreads();
  }
  if (tid < nb) partials[tid] = (tid > 0) ? tmp[tid - 1] : 0;  // exclusive
}

// scan finalize + cursor/deg_inv init (merged k_prep): thread i owns offs[i+1]
__global__ void k_scan_add(int* __restrict__ offs, const int* __restrict__ partials,
                           const int* __restrict__ cnt, int* __restrict__ cursor,
                           float* __restrict__ deg_inv) {
  int i = blockIdx.x * blockDim.x + threadIdx.x;
  if (i == 0) {
    offs[0] = 0;
    cursor[0] = 0;
    deg_inv[0] = 1.0f / (float)max(cnt[0], 1);
  }
  if (i < N_NODES) {
    int v = offs[i + 1] + partials[i >> 10];
    offs[i + 1] = v;
    if (i + 1 < N_NODES) {
      cursor[i + 1] = v;
      deg_inv[i + 1] = 1.0f / (float)max(cnt[i + 1], 1);
    }
  }
}

// Partitioned fill (r12 proven: plain loads; NT variant was neutral-negative).
#define FILL_BPP 224  // blocks per partition
__global__ void k_fill8(const int* __restrict__ src, const int* __restrict__ dst,
                        int* __restrict__ cursor, int* __restrict__ esrc) {
  const int part = blockIdx.x & 7;
  const int bp = blockIdx.x >> 3;
  const int lo = part * (N_NODES / 8);
  const int hi = lo + (N_NODES / 8);
  for (int i = bp * 256 + threadIdx.x; i < N_EDGES; i += FILL_BPP * 256) {
    int d = dst[i];
    if (d >= lo && d < hi) {
      int p = atomicAdd(&cursor[d], 1);
      esrc[p] = src[i];
    }
  }
}

// ---------------- fused preprocessing: zero cnt | x->f16 | weight pack ----------------
// Activations now SINGLE f16 plane (lo-plane dropped; error audit: activations
// stay O(1-4), f16 rounding ~1e-3/layer, ~4e-3 total — under the 0.0156
// reference-noise floor carried since the fp32 round).
// Weight pack (hi planes only): per layer mats {0:ws_hi, 1:wn_hi};
// holds W[k = t*32 + (lane>>4)*8 + j][col = f*16 + (lane&15)]

#define WP_MAT (4 * 8 * 64 * 8)  // 16384 halfs / matrix
#define WP_LAYER (2 * WP_MAT)    // 32768 halfs / layer

#define NZ_BLOCKS ((N_NODES + 255) / 256)            // 391
#define NX_BLOCKS ((N_NODES * DIM / 4 + 255) / 256)  // 12500
#define NW_BLOCKS 64

__global__ void k_preproc(int* __restrict__ cnt, const float* __restrict__ x,
                          _Float16* __restrict__ x1,
                          const float* __restrict__ ws0, const float* __restrict__ wn0,
                          const float* __restrict__ ws1, const float* __restrict__ wn1,
                          const float* __restrict__ ws2, const float* __restrict__ wn2,
                          const float* __restrict__ ws3, const float* __restrict__ wn3,
                          _Float16* __restrict__ wp) {
  const int bid = blockIdx.x;
  if (bid < NZ_BLOCKS) {
    int i = bid * 256 + threadIdx.x;
    if (i < N_NODES) cnt[i] = 0;
  } else if (bid < NZ_BLOCKS + NX_BLOCKS) {
    int i = (bid - NZ_BLOCKS) * 256 + threadIdx.x;
    if (i < (N_NODES * DIM) / 4) {
      float4 v = reinterpret_cast<const float4*>(x)[i];
      union { _Float16 h[4]; uint2 u; } a;
      a.h[0] = (_Float16)v.x;
      a.h[1] = (_Float16)v.y;
      a.h[2] = (_Float16)v.z;
      a.h[3] = (_Float16)v.w;
      reinterpret_cast<uint2*>(x1)[i] = a.u;
    }
  } else {
    int tid = (bid - NZ_BLOCKS - NX_BLOCKS) * 256 + threadIdx.x;  // 0..16383
    int l = tid & 63;
    int f = (tid >> 6) & 7;
    int t = (tid >> 9) & 3;
    int m = (tid >> 11) & 1;  // 0 = ws, 1 = wn
    int layer = tid >> 12;
    const float* srcs[8] = {ws0, wn0, ws1, wn1, ws2, wn2, ws3, wn3};
    const float* src = srcs[layer * 2 + m];
    _Float16* dstp =
        wp + (size_t)layer * WP_LAYER + ((((m * 4 + t) * 8 + f) * 64 + l) * 8);
    int k0 = t * 32 + (l >> 4) * 8;
    int col = f * 16 + (l & 15);
#pragma unroll
    for (int j = 0; j < 8; ++j) dstp[j] = (_Float16)src[(k0 + j) * DIM + col];
  }
}

// ---------------- aggregation: one wave per node, f16 gather, unroll 8 (proven) ----------------

__device__ __forceinline__ float f16lo(unsigned w) {
  union { unsigned u; _Float16 h[2]; } c;
  c.u = w;
  return (float)c.h[0];
}
__device__ __forceinline__ float f16hi(unsigned w) {
  union { unsigned u; _Float16 h[2]; } c;
  c.u = w;
  return (float)c.h[1];
}

__global__ void k_agg_f16(const _Float16* __restrict__ h1, const int* __restrict__ offs,
                          const int* __restrict__ esrc, const float* __restrict__ deg_inv,
                          _Float16* __restrict__ m1) {
  int wid = (blockIdx.x * blockDim.x + threadIdx.x) >> 6;  // node id
  int lane = threadIdx.x & 63;
  if (wid >= N_NODES) return;
  const unsigned* H = reinterpret_cast<const unsigned*>(h1);  // row = 64 u32
  int beg = offs[wid], end = offs[wid + 1];
  float xs[8] = {0.f, 0.f, 0.f, 0.f, 0.f, 0.f, 0.f, 0.f};
  float ys[8] = {0.f, 0.f, 0.f, 0.f, 0.f, 0.f, 0.f, 0.f};
  int e = beg;
  for (; e + 7 < end; e += 8) {
    int s[8];
#pragma unroll
    for (int j = 0; j < 8; ++j) s[j] = esrc[e + j];
    unsigned w[8];
#pragma unroll
    for (int j = 0; j < 8; ++j) w[j] = H[(size_t)s[j] * 64 + lane];
#pragma unroll
    for (int j = 0; j < 8; ++j) {
      xs[j] += f16lo(w[j]);
      ys[j] += f16hi(w[j]);
    }
  }
  for (; e + 1 < end; e += 2) {
    unsigned w0 = H[(size_t)esrc[e] * 64 + lane];
    unsigned w1 = H[(size_t)esrc[e + 1] * 64 + lane];
    xs[0] += f16lo(w0); ys[0] += f16hi(w0);
    xs[1] += f16lo(w1); ys[1] += f16hi(w1);
  }
  if (e < end) {
    unsigned w0 = H[(size_t)esrc[e] * 64 + lane];
    xs[2] += f16lo(w0); ys[2] += f16hi(w0);
  }
  float di = deg_inv[wid];
  float rx = ((xs[0] + xs[1]) + (xs[2] + xs[3])) + ((xs[4] + xs[5]) + (xs[6] + xs[7]));
  float ry = ((ys[0] + ys[1]) + (ys[2] + ys[3])) + ((ys[4] + ys[5]) + (ys[6] + ys[7]));
  rx *= di;
  ry *= di;
  union { unsigned u; _Float16 h[2]; } o;
  o.h[0] = (_Float16)rx;
  o.h[1] = (_Float16)ry;
  reinterpret_cast<unsigned*>(m1)[(size_t)wid * 64 + lane] = o.u;
}

// ---------------- MFMA dual-GEMM v8: single-plane f16, 2 MFMAs/frag ----------------
// out = act(h@ws + mean@wn + b); h = h1 (single f16 plane), mean = m1 (f16).
// acc += h1*ws_hi + m*wn_hi   (2 MFMAs per frag)
// Block = 64 rows, 256 threads = 4 waves; wave = 32 rows x 64 cols.
// h1 full-K staged upfront (16 KB LDS -> 6 blocks/CU with launch_bounds(256,6)),
// ONE barrier, barrier-free t-loop; mean A-frags direct from global.
// XOR swizzle chunk^=(row&7) on the GLOBAL source (global_load_lds dest stays
// linear); reads use the same XOR -> conflict-free ds_read_b128.

template <int RELU, int LAST>
__global__ __launch_bounds__(256, 6) void k_gemm_f16(
    const _Float16* __restrict__ hp1, const _Float16* __restrict__ mp1,
    const _Float16* __restrict__ wp, const float* __restrict__ bias,
    float* __restrict__ outf, _Float16* __restrict__ o1) {
  __shared__ _Float16 sA[64 * 128];  // 16 KB: [row*128 + k], swizzled

  const int tid = threadIdx.x;
  const int lane = tid & 63;
  const int wv = tid >> 6;
  const int wr = wv >> 1;  // rows wr*32..wr*32+31
  const int wc = wv & 1;   // cols wc*64..wc*64+63
  const int row0 = blockIdx.x * 64;
  const int lr = lane & 15;
  const int lg = lane >> 4;

  // ---- stage h1 full K (1024 slots of 16B) ----
#pragma unroll
  for (int i = 0; i < 4; ++i) {
    int s = i * 256 + tid;             // slot 0..1023
    int row = s >> 4;                  // 0..63
    int chunk = (s & 15) ^ (row & 7);  // swizzle on global side
    const _Float16* g = hp1 + (size_t)(row0 + row) * DIM + chunk * 8;
    _Float16* l = &sA[(size_t)(i * 256 + (tid & ~63)) * 8];
    stage16(g, l);
  }
  __syncthreads();  // single drain; loop below is barrier-free

  f32x4 acc[2][4];
#pragma unroll
  for (int i = 0; i < 2; ++i)
#pragma unroll
    for (int j = 0; j < 4; ++j) acc[i][j] = (f32x4){0.f, 0.f, 0.f, 0.f};

  const _Float16* WS1 = wp;           // ws hi
  const _Float16* WN1 = wp + WP_MAT;  // wn hi

#pragma unroll
  for (int t = 0; t < 4; ++t) {
    // mean A-frags direct from global (issued first; overlap with LDS reads + B)
    f16x8 am[2];
#pragma unroll
    for (int ri = 0; ri < 2; ++ri) {
      int row = row0 + wr * 32 + ri * 16 + lr;
      am[ri] = *reinterpret_cast<const f16x8*>(mp1 + (size_t)row * DIM + t * 32 + lg * 8);
    }
    // h A-frags from LDS (swizzled read; conflict-free)
    f16x8 a1[2];
#pragma unroll
    for (int ri = 0; ri < 2; ++ri) {
      int row_l = wr * 32 + ri * 16 + lr;
      int boff = (row_l << 8) + ((t * 64 + lg * 16) ^ ((row_l & 7) << 4));
      a1[ri] = *reinterpret_cast<const f16x8*>(
          reinterpret_cast<const char*>(&sA[0]) + boff);
    }
    // B frags from global (L2) + MFMA
#pragma unroll
    for (int fc = 0; fc < 4; ++fc) {
      int f = wc * 4 + fc;
      size_t boff = (size_t)((t * 8 + f) * 64 + lane) * 8;
      f16x8 bs1 = *reinterpret_cast<const f16x8*>(WS1 + boff);
      f16x8 bn1 = *reinterpret_cast<const f16x8*>(WN1 + boff);
#pragma unroll
      for (int ri = 0; ri < 2; ++ri) {
        acc[ri][fc] =
            __builtin_amdgcn_mfma_f32_16x16x32_f16(a1[ri], bs1, acc[ri][fc], 0, 0, 0);
        acc[ri][fc] =
            __builtin_amdgcn_mfma_f32_16x16x32_f16(am[ri], bn1, acc[ri][fc], 0, 0, 0);
      }
    }
  }

  // ---- epilogue: C/D layout col=lane&15, row=(lane>>4)*4+reg ----
  float bv[4];
#pragma unroll
  for (int fc = 0; fc < 4; ++fc) bv[fc] = bias[wc * 64 + fc * 16 + lr];
#pragma unroll
  for (int ri = 0; ri < 2; ++ri)
#pragma unroll
    for (int fc = 0; fc < 4; ++fc)
#pragma unroll
      for (int r = 0; r < 4; ++r) {
        int row = row0 + wr * 32 + ri * 16 + lg * 4 + r;
        if (row < N_NODES) {
          float v = acc[ri][fc][r] + bv[fc];
          if (RELU) v = fmaxf(v, 0.f);
          size_t idx = (size_t)row * DIM + wc * 64 + fc * 16 + lr;
          if (LAST)
            outf[idx] = v;
          else
            o1[idx] = (_Float16)v;
        }
      }
}

// ---------------- driver ----------------

extern "C" void kernel_launch(void* const* d_in, const int* in_sizes, int n_in,
                              void* d_out, int out_size, void* d_ws, size_t ws_size,
                              hipStream_t stream) {
  const float* x = (const float*)d_in[0];
  const int* src = (const int*)d_in[1];
  const int* dst = (const int*)d_in[2];
  const float* Ws[4];
  const float* Wn[4];
  const float* Bi[4];
  for (int i = 0; i < 4; ++i) {
    Ws[i] = (const float*)d_in[3 + 3 * i];
    Wn[i] = (const float*)d_in[4 + 3 * i];
    Bi[i] = (const float*)d_in[5 + 3 * i];
  }
  float* out = (float*)d_out;

  char* p = (char*)d_ws;
  auto take = [&](size_t bytes) {
    void* r = (void*)p;
    p += (bytes + 255) & ~(size_t)255;
    return r;
  };
  int* cnt = (int*)take((size_t)N_NODES * 4);
  int* offs = (int*)take((size_t)(N_NODES + 1) * 4);
  int* cursor = (int*)take((size_t)N_NODES * 4);
  int* partials = (int*)take(128 * 4);
  float* deg_inv = (float*)take((size_t)N_NODES * 4);
  int* esrc = (int*)take((size_t)N_EDGES * 4);
  _Float16* hA1 = (_Float16*)take((size_t)N_NODES * DIM * 2);
  _Float16* hB1 = (_Float16*)take((size_t)N_NODES * DIM * 2);
  _Float16* m1 = (_Float16*)take((size_t)N_NODES * DIM * 2);
  _Float16* wpk = (_Float16*)take((size_t)4 * WP_LAYER * 2);
  // pad so last-block OOB staging/mean reads stay inside the workspace
  (void)take((size_t)64 * 1024);

  const int NB = (N_NODES + 1023) / 1024;  // 98

  // fused preprocessing (cnt zero | x->f16 | weight pack), then CSR build
  k_preproc<<<NZ_BLOCKS + NX_BLOCKS + NW_BLOCKS, 256, 0, stream>>>(
      cnt, x, hA1, Ws[0], Wn[0], Ws[1], Wn[1], Ws[2], Wn[2], Ws[3], Wn[3], wpk);
  k_count<<<(N_EDGES + 255) / 256, 256, 0, stream>>>(dst, cnt);
  k_scan_blk<<<NB, 1024, 0, stream>>>(cnt, offs, partials);
  k_scan_part<<<1, 128, 0, stream>>>(partials, NB);
  k_scan_add<<<(N_NODES + 255) / 256, 256, 0, stream>>>(offs, partials, cnt, cursor,
                                                        deg_inv);
  k_fill8<<<8 * FILL_BPP, 256, 0, stream>>>(src, dst, cursor, esrc);

  const int AGG_BLOCKS = (N_NODES + 3) / 4;     // 4 waves/block, 1 node/wave
  const int GEMM_BLOCKS = (N_NODES + 63) / 64;  // 64 rows x 128 cols per block

  _Float16 *h1 = hA1, *n1 = hB1;
  for (int l = 0; l < 4; ++l) {
    k_agg_f16<<<AGG_BLOCKS, 256, 0, stream>>>(h1, offs, esrc, deg_inv, m1);
    const _Float16* wl = wpk + (size_t)l * WP_LAYER;
    if (l < 3) {
      k_gemm_f16<1, 0><<<GEMM_BLOCKS, 256, 0, stream>>>(h1, m1, wl, Bi[l], nullptr, n1);
      _Float16* t1 = h1; h1 = n1; n1 = t1;
    } else {
      k_gemm_f16<0, 1><<<GEMM_BLOCKS, 256, 0, stream>>>(h1, m1, wl, Bi[l], out, nullptr);
    }
  }
}

// Round 16
// 518.559 us; speedup vs baseline: 1.0975x; 1.0118x over previous
//
#include <hip/hip_runtime.h>

#define N_NODES 100000
#define N_EDGES 1600000
#define DIM 128

typedef __attribute__((ext_vector_type(8))) _Float16 f16x8;  // MFMA A/B frag (4 VGPRs)
typedef __attribute__((ext_vector_type(4))) float f32x4;     // MFMA C/D frag
typedef __attribute__((ext_vector_type(2))) float f32x2;

// async global->LDS DMA, 16B per lane (dest = wave-uniform base + lane*16)
__device__ __forceinline__ void stage16(const _Float16* g, _Float16* l) {
  __builtin_amdgcn_global_load_lds(
      (const __attribute__((address_space(1))) void*)g,
      (__attribute__((address_space(3))) void*)l, 16, 0, 0);
}

// ---------------- fp8 e4m3 (OCP) conversion helpers ----------------
#if __has_builtin(__builtin_amdgcn_cvt_pk_f32_fp8) && \
    __has_builtin(__builtin_amdgcn_cvt_pk_fp8_f32)
#define HW_FP8 1
#endif

__device__ __forceinline__ f32x2 fp8x2_to_f32(unsigned w) {  // 2 fp8 in low bytes
#ifdef HW_FP8
  return __builtin_amdgcn_cvt_pk_f32_fp8((int)w, false);
#else
  f32x2 r;
#pragma unroll
  for (int k = 0; k < 2; ++k) {
    unsigned b = (w >> (8 * k)) & 0xffu;
    unsigned s = b >> 7, e = (b >> 3) & 15u, m = b & 7u;
    float v;
    if (e)
      v = __uint_as_float(((e + 120u) << 23) | (m << 20));
    else
      v = (float)m * 0.001953125f;  // denorm: m * 2^-9
    r[k] = s ? -v : v;
  }
  return r;
#endif
}

__device__ __forceinline__ unsigned char f32_to_fp8(float f) {
#ifdef HW_FP8
  int p = __builtin_amdgcn_cvt_pk_fp8_f32(f, f, 0, false);
  return (unsigned char)(p & 0xff);
#else
  _Float16 hf = (_Float16)f;
  unsigned short h;
  __builtin_memcpy(&h, &hf, 2);
  unsigned s = (h >> 8) & 0x80u;
  int comb = h & 0x7fff;                       // E(5)|m(10)
  if (comb >= (31 << 10)) return (unsigned char)(s | 0x7e);  // inf/nan -> 448
  comb = comb + 0x3f + ((comb >> 7) & 1);      // RNE to 3-bit mantissa
  int ef = (comb >> 7) - (8 << 3);             // rebias E-15+7 in (E<<3)|m3
  if (ef <= 0) return (unsigned char)s;        // flush subnormal -> 0
  if (ef > 0x7e) ef = 0x7e;                    // saturate 448
  return (unsigned char)(s | ef);
#endif
}

__device__ __forceinline__ unsigned f32x4_to_fp8x4(float a, float b, float c, float d) {
#ifdef HW_FP8
  int p = __builtin_amdgcn_cvt_pk_fp8_f32(a, b, 0, false);
  p = __builtin_amdgcn_cvt_pk_fp8_f32(c, d, p, true);
  return (unsigned)p;
#else
  return (unsigned)f32_to_fp8(a) | ((unsigned)f32_to_fp8(b) << 8) |
         ((unsigned)f32_to_fp8(c) << 16) | ((unsigned)f32_to_fp8(d) << 24);
#endif
}

// ---------------- CSR build ----------------

__global__ void k_count(const int* __restrict__ dst, int* __restrict__ cnt) {
  int i = blockIdx.x * blockDim.x + threadIdx.x;
  if (i < N_EDGES) atomicAdd(&cnt[dst[i]], 1);
}

__global__ void k_scan_blk(const int* __restrict__ cnt, int* __restrict__ offs,
                           int* __restrict__ partials) {
  int tid = threadIdx.x;
  int gid = blockIdx.x * 1024 + tid;
  int v = (gid < N_NODES) ? cnt[gid] : 0;
  int lane = tid & 63, w = tid >> 6;
  int s = v;
#pragma unroll
  for (int d = 1; d < 64; d <<= 1) {
    int t = __shfl_up(s, d);
    if (lane >= d) s += t;
  }
  __shared__ int wsum[16];
  if (lane == 63) wsum[w] = s;
  __syncthreads();
  if (tid < 16) {
    int t2 = wsum[tid];
#pragma unroll
    for (int d = 1; d < 16; d <<= 1) {
      int u = __shfl_up(t2, d);
      if (tid >= d) t2 += u;
    }
    wsum[tid] = t2;
  }
  __syncthreads();
  if (w > 0) s += wsum[w - 1];
  if (gid < N_NODES) offs[gid + 1] = s;
  if (tid == 1023) partials[blockIdx.x] = s;
}

__global__ void k_scan_part(int* __restrict__ partials, int nb) {
  __shared__ int tmp[128];
  int tid = threadIdx.x;
  tmp[tid] = (tid < nb) ? partials[tid] : 0;
  __syncthreads();
  for (int d = 1; d < 128; d <<= 1) {
    int t = (tid >= d) ? tmp[tid - d] : 0;
    __syncthreads();
    tmp[tid] += t;
    __syncthreads();
  }
  if (tid < nb) partials[tid] = (tid > 0) ? tmp[tid - 1] : 0;  // exclusive
}

// scan finalize + cursor/deg_inv init (merged k_prep): thread i owns offs[i+1]
__global__ void k_scan_add(int* __restrict__ offs, const int* __restrict__ partials,
                           const int* __restrict__ cnt, int* __restrict__ cursor,
                           float* __restrict__ deg_inv) {
  int i = blockIdx.x * blockDim.x + threadIdx.x;
  if (i == 0) {
    offs[0] = 0;
    cursor[0] = 0;
    deg_inv[0] = 1.0f / (float)max(cnt[0], 1);
  }
  if (i < N_NODES) {
    int v = offs[i + 1] + partials[i >> 10];
    offs[i + 1] = v;
    if (i + 1 < N_NODES) {
      cursor[i + 1] = v;
      deg_inv[i + 1] = 1.0f / (float)max(cnt[i + 1], 1);
    }
  }
}

// Partitioned fill (proven floor: plain loads).
#define FILL_BPP 224  // blocks per partition
__global__ void k_fill8(const int* __restrict__ src, const int* __restrict__ dst,
                        int* __restrict__ cursor, int* __restrict__ esrc) {
  const int part = blockIdx.x & 7;
  const int bp = blockIdx.x >> 3;
  const int lo = part * (N_NODES / 8);
  const int hi = lo + (N_NODES / 8);
  for (int i = bp * 256 + threadIdx.x; i < N_EDGES; i += FILL_BPP * 256) {
    int d = dst[i];
    if (d >= lo && d < hi) {
      int p = atomicAdd(&cursor[d], 1);
      esrc[p] = src[i];
    }
  }
}

// ---------------- fused preprocessing: zero cnt | x->f16 + fp8 | weight pack ----------------
// Weight pack (hi planes only): per layer mats {0:ws_hi, 1:wn_hi};
// holds W[k = t*32 + (lane>>4)*8 + j][col = f*16 + (lane&15)]

#define WP_MAT (4 * 8 * 64 * 8)  // 16384 halfs / matrix
#define WP_LAYER (2 * WP_MAT)    // 32768 halfs / layer

#define NZ_BLOCKS ((N_NODES + 255) / 256)            // 391
#define NX_BLOCKS ((N_NODES * DIM / 4 + 255) / 256)  // 12500
#define NW_BLOCKS 64

__global__ void k_preproc(int* __restrict__ cnt, const float* __restrict__ x,
                          _Float16* __restrict__ x1, unsigned char* __restrict__ x8,
                          const float* __restrict__ ws0, const float* __restrict__ wn0,
                          const float* __restrict__ ws1, const float* __restrict__ wn1,
                          const float* __restrict__ ws2, const float* __restrict__ wn2,
                          const float* __restrict__ ws3, const float* __restrict__ wn3,
                          _Float16* __restrict__ wp) {
  const int bid = blockIdx.x;
  if (bid < NZ_BLOCKS) {
    int i = bid * 256 + threadIdx.x;
    if (i < N_NODES) cnt[i] = 0;
  } else if (bid < NZ_BLOCKS + NX_BLOCKS) {
    int i = (bid - NZ_BLOCKS) * 256 + threadIdx.x;
    if (i < (N_NODES * DIM) / 4) {
      float4 v = reinterpret_cast<const float4*>(x)[i];
      union { _Float16 h[4]; uint2 u; } a;
      a.h[0] = (_Float16)v.x;
      a.h[1] = (_Float16)v.y;
      a.h[2] = (_Float16)v.z;
      a.h[3] = (_Float16)v.w;
      reinterpret_cast<uint2*>(x1)[i] = a.u;
      reinterpret_cast<unsigned*>(x8)[i] = f32x4_to_fp8x4(v.x, v.y, v.z, v.w);
    }
  } else {
    int tid = (bid - NZ_BLOCKS - NX_BLOCKS) * 256 + threadIdx.x;  // 0..16383
    int l = tid & 63;
    int f = (tid >> 6) & 7;
    int t = (tid >> 9) & 3;
    int m = (tid >> 11) & 1;  // 0 = ws, 1 = wn
    int layer = tid >> 12;
    const float* srcs[8] = {ws0, wn0, ws1, wn1, ws2, wn2, ws3, wn3};
    const float* src = srcs[layer * 2 + m];
    _Float16* dstp =
        wp + (size_t)layer * WP_LAYER + ((((m * 4 + t) * 8 + f) * 64 + l) * 8);
    int k0 = t * 32 + (l >> 4) * 8;
    int col = f * 16 + (l & 15);
#pragma unroll
    for (int j = 0; j < 8; ++j) dstp[j] = (_Float16)src[(k0 + j) * DIM + col];
  }
}

// ---------------- aggregation: one wave per node, fp8 gather (128B/edge), unroll 8 ----------------
// Same proven r10 structure; table is the fp8 copy of h -> half the gather bytes.

__global__ void k_agg_fp8(const unsigned char* __restrict__ h8,
                          const int* __restrict__ offs, const int* __restrict__ esrc,
                          const float* __restrict__ deg_inv, _Float16* __restrict__ m1) {
  int wid = (blockIdx.x * blockDim.x + threadIdx.x) >> 6;  // node id
  int lane = threadIdx.x & 63;
  if (wid >= N_NODES) return;
  const unsigned short* H = reinterpret_cast<const unsigned short*>(h8);  // row = 64 u16
  int beg = offs[wid], end = offs[wid + 1];
  float xs[8] = {0.f, 0.f, 0.f, 0.f, 0.f, 0.f, 0.f, 0.f};
  float ys[8] = {0.f, 0.f, 0.f, 0.f, 0.f, 0.f, 0.f, 0.f};
  int e = beg;
  for (; e + 7 < end; e += 8) {
    int s[8];
#pragma unroll
    for (int j = 0; j < 8; ++j) s[j] = esrc[e + j];
    unsigned short w[8];
#pragma unroll
    for (int j = 0; j < 8; ++j) w[j] = H[(size_t)s[j] * 64 + lane];
#pragma unroll
    for (int j = 0; j < 8; ++j) {
      f32x2 v = fp8x2_to_f32((unsigned)w[j]);
      xs[j] += v[0];
      ys[j] += v[1];
    }
  }
  for (; e + 1 < end; e += 2) {
    f32x2 v0 = fp8x2_to_f32((unsigned)H[(size_t)esrc[e] * 64 + lane]);
    f32x2 v1 = fp8x2_to_f32((unsigned)H[(size_t)esrc[e + 1] * 64 + lane]);
    xs[0] += v0[0]; ys[0] += v0[1];
    xs[1] += v1[0]; ys[1] += v1[1];
  }
  if (e < end) {
    f32x2 v0 = fp8x2_to_f32((unsigned)H[(size_t)esrc[e] * 64 + lane]);
    xs[2] += v0[0]; ys[2] += v0[1];
  }
  float di = deg_inv[wid];
  float rx = ((xs[0] + xs[1]) + (xs[2] + xs[3])) + ((xs[4] + xs[5]) + (xs[6] + xs[7]));
  float ry = ((ys[0] + ys[1]) + (ys[2] + ys[3])) + ((ys[4] + ys[5]) + (ys[6] + ys[7]));
  rx *= di;
  ry *= di;
  union { unsigned u; _Float16 h[2]; } o;
  o.h[0] = (_Float16)rx;
  o.h[1] = (_Float16)ry;
  reinterpret_cast<unsigned*>(m1)[(size_t)wid * 64 + lane] = o.u;
}

// ---------------- MFMA dual-GEMM v8: single-plane f16, 2 MFMAs/frag ----------------
// out = act(h@ws + mean@wn + b); h = h1 (f16), mean = m1 (f16).
// acc += h1*ws_hi + m*wn_hi   (2 MFMAs per frag)
// Epilogue (l<3) writes o1 f16 (next GEMM self input) AND o8 fp8 (next agg
// gather table). h1 full-K staged upfront (16 KB LDS, 6 blk/CU), ONE barrier,
// barrier-free t-loop; mean A-frags direct from global. XOR swizzle
// chunk^=(row&7) on the GLOBAL source; reads use the same XOR.

template <int RELU, int LAST>
__global__ __launch_bounds__(256, 6) void k_gemm_f16(
    const _Float16* __restrict__ hp1, const _Float16* __restrict__ mp1,
    const _Float16* __restrict__ wp, const float* __restrict__ bias,
    float* __restrict__ outf, _Float16* __restrict__ o1,
    unsigned char* __restrict__ o8) {
  __shared__ _Float16 sA[64 * 128];  // 16 KB: [row*128 + k], swizzled

  const int tid = threadIdx.x;
  const int lane = tid & 63;
  const int wv = tid >> 6;
  const int wr = wv >> 1;  // rows wr*32..wr*32+31
  const int wc = wv & 1;   // cols wc*64..wc*64+63
  const int row0 = blockIdx.x * 64;
  const int lr = lane & 15;
  const int lg = lane >> 4;

  // ---- stage h1 full K (1024 slots of 16B) ----
#pragma unroll
  for (int i = 0; i < 4; ++i) {
    int s = i * 256 + tid;             // slot 0..1023
    int row = s >> 4;                  // 0..63
    int chunk = (s & 15) ^ (row & 7);  // swizzle on global side
    const _Float16* g = hp1 + (size_t)(row0 + row) * DIM + chunk * 8;
    _Float16* l = &sA[(size_t)(i * 256 + (tid & ~63)) * 8];
    stage16(g, l);
  }
  __syncthreads();  // single drain; loop below is barrier-free

  f32x4 acc[2][4];
#pragma unroll
  for (int i = 0; i < 2; ++i)
#pragma unroll
    for (int j = 0; j < 4; ++j) acc[i][j] = (f32x4){0.f, 0.f, 0.f, 0.f};

  const _Float16* WS1 = wp;           // ws hi
  const _Float16* WN1 = wp + WP_MAT;  // wn hi

#pragma unroll
  for (int t = 0; t < 4; ++t) {
    // mean A-frags direct from global (issued first; overlap with LDS reads + B)
    f16x8 am[2];
#pragma unroll
    for (int ri = 0; ri < 2; ++ri) {
      int row = row0 + wr * 32 + ri * 16 + lr;
      am[ri] = *reinterpret_cast<const f16x8*>(mp1 + (size_t)row * DIM + t * 32 + lg * 8);
    }
    // h A-frags from LDS (swizzled read; conflict-free)
    f16x8 a1[2];
#pragma unroll
    for (int ri = 0; ri < 2; ++ri) {
      int row_l = wr * 32 + ri * 16 + lr;
      int boff = (row_l << 8) + ((t * 64 + lg * 16) ^ ((row_l & 7) << 4));
      a1[ri] = *reinterpret_cast<const f16x8*>(
          reinterpret_cast<const char*>(&sA[0]) + boff);
    }
    // B frags from global (L2) + MFMA
#pragma unroll
    for (int fc = 0; fc < 4; ++fc) {
      int f = wc * 4 + fc;
      size_t boff = (size_t)((t * 8 + f) * 64 + lane) * 8;
      f16x8 bs1 = *reinterpret_cast<const f16x8*>(WS1 + boff);
      f16x8 bn1 = *reinterpret_cast<const f16x8*>(WN1 + boff);
#pragma unroll
      for (int ri = 0; ri < 2; ++ri) {
        acc[ri][fc] =
            __builtin_amdgcn_mfma_f32_16x16x32_f16(a1[ri], bs1, acc[ri][fc], 0, 0, 0);
        acc[ri][fc] =
            __builtin_amdgcn_mfma_f32_16x16x32_f16(am[ri], bn1, acc[ri][fc], 0, 0, 0);
      }
    }
  }

  // ---- epilogue: C/D layout col=lane&15, row=(lane>>4)*4+reg ----
  float bv[4];
#pragma unroll
  for (int fc = 0; fc < 4; ++fc) bv[fc] = bias[wc * 64 + fc * 16 + lr];
#pragma unroll
  for (int ri = 0; ri < 2; ++ri)
#pragma unroll
    for (int fc = 0; fc < 4; ++fc)
#pragma unroll
      for (int r = 0; r < 4; ++r) {
        int row = row0 + wr * 32 + ri * 16 + lg * 4 + r;
        if (row < N_NODES) {
          float v = acc[ri][fc][r] + bv[fc];
          if (RELU) v = fmaxf(v, 0.f);
          size_t idx = (size_t)row * DIM + wc * 64 + fc * 16 + lr;
          if (LAST) {
            outf[idx] = v;
          } else {
            o1[idx] = (_Float16)v;
            o8[idx] = f32_to_fp8(v);
          }
        }
      }
}

// ---------------- driver ----------------

extern "C" void kernel_launch(void* const* d_in, const int* in_sizes, int n_in,
                              void* d_out, int out_size, void* d_ws, size_t ws_size,
                              hipStream_t stream) {
  const float* x = (const float*)d_in[0];
  const int* src = (const int*)d_in[1];
  const int* dst = (const int*)d_in[2];
  const float* Ws[4];
  const float* Wn[4];
  const float* Bi[4];
  for (int i = 0; i < 4; ++i) {
    Ws[i] = (const float*)d_in[3 + 3 * i];
    Wn[i] = (const float*)d_in[4 + 3 * i];
    Bi[i] = (const float*)d_in[5 + 3 * i];
  }
  float* out = (float*)d_out;

  char* p = (char*)d_ws;
  auto take = [&](size_t bytes) {
    void* r = (void*)p;
    p += (bytes + 255) & ~(size_t)255;
    return r;
  };
  int* cnt = (int*)take((size_t)N_NODES * 4);
  int* offs = (int*)take((size_t)(N_NODES + 1) * 4);
  int* cursor = (int*)take((size_t)N_NODES * 4);
  int* partials = (int*)take(128 * 4);
  float* deg_inv = (float*)take((size_t)N_NODES * 4);
  int* esrc = (int*)take((size_t)N_EDGES * 4);
  _Float16* hA1 = (_Float16*)take((size_t)N_NODES * DIM * 2);
  _Float16* hB1 = (_Float16*)take((size_t)N_NODES * DIM * 2);
  unsigned char* h8A = (unsigned char*)take((size_t)N_NODES * DIM);
  unsigned char* h8B = (unsigned char*)take((size_t)N_NODES * DIM);
  _Float16* m1 = (_Float16*)take((size_t)N_NODES * DIM * 2);
  _Float16* wpk = (_Float16*)take((size_t)4 * WP_LAYER * 2);
  // pad so last-block OOB staging/mean reads stay inside the workspace
  (void)take((size_t)64 * 1024);

  const int NB = (N_NODES + 1023) / 1024;  // 98

  // fused preprocessing (cnt zero | x->f16+fp8 | weight pack), then CSR build
  k_preproc<<<NZ_BLOCKS + NX_BLOCKS + NW_BLOCKS, 256, 0, stream>>>(
      cnt, x, hA1, h8A, Ws[0], Wn[0], Ws[1], Wn[1], Ws[2], Wn[2], Ws[3], Wn[3], wpk);
  k_count<<<(N_EDGES + 255) / 256, 256, 0, stream>>>(dst, cnt);
  k_scan_blk<<<NB, 1024, 0, stream>>>(cnt, offs, partials);
  k_scan_part<<<1, 128, 0, stream>>>(partials, NB);
  k_scan_add<<<(N_NODES + 255) / 256, 256, 0, stream>>>(offs, partials, cnt, cursor,
                                                        deg_inv);
  k_fill8<<<8 * FILL_BPP, 256, 0, stream>>>(src, dst, cursor, esrc);

  const int AGG_BLOCKS = (N_NODES + 3) / 4;     // 4 waves/block, 1 node/wave
  const int GEMM_BLOCKS = (N_NODES + 63) / 64;  // 64 rows x 128 cols per block

  _Float16 *h1 = hA1, *n1 = hB1;
  unsigned char *h8 = h8A, *n8 = h8B;
  for (int l = 0; l < 4; ++l) {
    k_agg_fp8<<<AGG_BLOCKS, 256, 0, stream>>>(h8, offs, esrc, deg_inv, m1);
    const _Float16* wl = wpk + (size_t)l * WP_LAYER;
    if (l < 3) {
      k_gemm_f16<1, 0><<<GEMM_BLOCKS, 256, 0, stream>>>(h1, m1, wl, Bi[l], nullptr, n1,
                                                        n8);
      _Float16* t1 = h1; h1 = n1; n1 = t1;
      unsigned char* t8 = h8; h8 = n8; n8 = t8;
    } else {
      k_gemm_f16<0, 1><<<GEMM_BLOCKS, 256, 0, stream>>>(h1, m1, wl, Bi[l], out, nullptr,
                                                        nullptr);
    }
  }
}

// Round 17
// 466.982 us; speedup vs baseline: 1.2187x; 1.1104x over previous
//
#include <hip/hip_runtime.h>

#define N_NODES 100000
#define N_EDGES 1600000
#define DIM 128

typedef __attribute__((ext_vector_type(8))) _Float16 f16x8;  // MFMA A/B frag (4 VGPRs)
typedef __attribute__((ext_vector_type(4))) float f32x4;     // MFMA C/D frag
typedef __attribute__((ext_vector_type(2))) float f32x2;

// async global->LDS DMA, 16B per lane (dest = wave-uniform base + lane*16)
__device__ __forceinline__ void stage16(const _Float16* g, _Float16* l) {
  __builtin_amdgcn_global_load_lds(
      (const __attribute__((address_space(1))) void*)g,
      (__attribute__((address_space(3))) void*)l, 16, 0, 0);
}

// ---------------- fp8 e4m3 (OCP) conversion helpers ----------------
#if __has_builtin(__builtin_amdgcn_cvt_pk_f32_fp8) && \
    __has_builtin(__builtin_amdgcn_cvt_pk_fp8_f32)
#define HW_FP8 1
#endif

__device__ __forceinline__ f32x2 fp8x2_lo(unsigned w) {
#ifdef HW_FP8
  return __builtin_amdgcn_cvt_pk_f32_fp8((int)w, false);
#else
  f32x2 r;
#pragma unroll
  for (int k = 0; k < 2; ++k) {
    unsigned b = (w >> (8 * k)) & 0xffu;
    unsigned s = b >> 7, e = (b >> 3) & 15u, m = b & 7u;
    float v;
    if (e)
      v = __uint_as_float(((e + 120u) << 23) | (m << 20));
    else
      v = (float)m * 0.001953125f;  // denorm: m * 2^-9
    r[k] = s ? -v : v;
  }
  return r;
#endif
}

__device__ __forceinline__ f32x2 fp8x2_hi(unsigned w) {
#ifdef HW_FP8
  return __builtin_amdgcn_cvt_pk_f32_fp8((int)w, true);
#else
  return fp8x2_lo(w >> 16);
#endif
}

__device__ __forceinline__ unsigned char f32_to_fp8(float f) {
#ifdef HW_FP8
  int p = __builtin_amdgcn_cvt_pk_fp8_f32(f, f, 0, false);
  return (unsigned char)(p & 0xff);
#else
  _Float16 hf = (_Float16)f;
  unsigned short h;
  __builtin_memcpy(&h, &hf, 2);
  unsigned s = (h >> 8) & 0x80u;
  int comb = h & 0x7fff;                       // E(5)|m(10)
  if (comb >= (31 << 10)) return (unsigned char)(s | 0x7e);  // inf/nan -> 448
  comb = comb + 0x3f + ((comb >> 7) & 1);      // RNE to 3-bit mantissa
  int ef = (comb >> 7) - (8 << 3);             // rebias E-15+7 in (E<<3)|m3
  if (ef <= 0) return (unsigned char)s;        // flush subnormal -> 0
  if (ef > 0x7e) ef = 0x7e;                    // saturate 448
  return (unsigned char)(s | ef);
#endif
}

__device__ __forceinline__ unsigned f32x4_to_fp8x4(float a, float b, float c, float d) {
#ifdef HW_FP8
  int p = __builtin_amdgcn_cvt_pk_fp8_f32(a, b, 0, false);
  p = __builtin_amdgcn_cvt_pk_fp8_f32(c, d, p, true);
  return (unsigned)p;
#else
  return (unsigned)f32_to_fp8(a) | ((unsigned)f32_to_fp8(b) << 8) |
         ((unsigned)f32_to_fp8(c) << 16) | ((unsigned)f32_to_fp8(d) << 24);
#endif
}

// ---------------- CSR build ----------------

__global__ void k_count(const int* __restrict__ dst, int* __restrict__ cnt) {
  int i = blockIdx.x * blockDim.x + threadIdx.x;
  if (i < N_EDGES) atomicAdd(&cnt[dst[i]], 1);
}

__global__ void k_scan_blk(const int* __restrict__ cnt, int* __restrict__ offs,
                           int* __restrict__ partials) {
  int tid = threadIdx.x;
  int gid = blockIdx.x * 1024 + tid;
  int v = (gid < N_NODES) ? cnt[gid] : 0;
  int lane = tid & 63, w = tid >> 6;
  int s = v;
#pragma unroll
  for (int d = 1; d < 64; d <<= 1) {
    int t = __shfl_up(s, d);
    if (lane >= d) s += t;
  }
  __shared__ int wsum[16];
  if (lane == 63) wsum[w] = s;
  __syncthreads();
  if (tid < 16) {
    int t2 = wsum[tid];
#pragma unroll
    for (int d = 1; d < 16; d <<= 1) {
      int u = __shfl_up(t2, d);
      if (tid >= d) t2 += u;
    }
    wsum[tid] = t2;
  }
  __syncthreads();
  if (w > 0) s += wsum[w - 1];
  if (gid < N_NODES) offs[gid + 1] = s;
  if (tid == 1023) partials[blockIdx.x] = s;
}

__global__ void k_scan_part(int* __restrict__ partials, int nb) {
  __shared__ int tmp[128];
  int tid = threadIdx.x;
  tmp[tid] = (tid < nb) ? partials[tid] : 0;
  __syncthreads();
  for (int d = 1; d < 128; d <<= 1) {
    int t = (tid >= d) ? tmp[tid - d] : 0;
    __syncthreads();
    tmp[tid] += t;
    __syncthreads();
  }
  if (tid < nb) partials[tid] = (tid > 0) ? tmp[tid - 1] : 0;  // exclusive
}

// scan finalize + cursor/deg_inv init (merged k_prep): thread i owns offs[i+1]
__global__ void k_scan_add(int* __restrict__ offs, const int* __restrict__ partials,
                           const int* __restrict__ cnt, int* __restrict__ cursor,
                           float* __restrict__ deg_inv) {
  int i = blockIdx.x * blockDim.x + threadIdx.x;
  if (i == 0) {
    offs[0] = 0;
    cursor[0] = 0;
    deg_inv[0] = 1.0f / (float)max(cnt[0], 1);
  }
  if (i < N_NODES) {
    int v = offs[i + 1] + partials[i >> 10];
    offs[i + 1] = v;
    if (i + 1 < N_NODES) {
      cursor[i + 1] = v;
      deg_inv[i + 1] = 1.0f / (float)max(cnt[i + 1], 1);
    }
  }
}

// Partitioned fill (proven floor: plain loads).
#define FILL_BPP 224  // blocks per partition
__global__ void k_fill8(const int* __restrict__ src, const int* __restrict__ dst,
                        int* __restrict__ cursor, int* __restrict__ esrc) {
  const int part = blockIdx.x & 7;
  const int bp = blockIdx.x >> 3;
  const int lo = part * (N_NODES / 8);
  const int hi = lo + (N_NODES / 8);
  for (int i = bp * 256 + threadIdx.x; i < N_EDGES; i += FILL_BPP * 256) {
    int d = dst[i];
    if (d >= lo && d < hi) {
      int p = atomicAdd(&cursor[d], 1);
      esrc[p] = src[i];
    }
  }
}

// ---------------- fused preprocessing: zero cnt | x->f16 + fp8 | weight pack ----------------
// Weight pack (hi planes only): per layer mats {0:ws_hi, 1:wn_hi};
// holds W[k = t*32 + (lane>>4)*8 + j][col = f*16 + (lane&15)]

#define WP_MAT (4 * 8 * 64 * 8)  // 16384 halfs / matrix
#define WP_LAYER (2 * WP_MAT)    // 32768 halfs / layer

#define NZ_BLOCKS ((N_NODES + 255) / 256)            // 391
#define NX_BLOCKS ((N_NODES * DIM / 4 + 255) / 256)  // 12500
#define NW_BLOCKS 64

__global__ void k_preproc(int* __restrict__ cnt, const float* __restrict__ x,
                          _Float16* __restrict__ x1, unsigned char* __restrict__ x8,
                          const float* __restrict__ ws0, const float* __restrict__ wn0,
                          const float* __restrict__ ws1, const float* __restrict__ wn1,
                          const float* __restrict__ ws2, const float* __restrict__ wn2,
                          const float* __restrict__ ws3, const float* __restrict__ wn3,
                          _Float16* __restrict__ wp) {
  const int bid = blockIdx.x;
  if (bid < NZ_BLOCKS) {
    int i = bid * 256 + threadIdx.x;
    if (i < N_NODES) cnt[i] = 0;
  } else if (bid < NZ_BLOCKS + NX_BLOCKS) {
    int i = (bid - NZ_BLOCKS) * 256 + threadIdx.x;
    if (i < (N_NODES * DIM) / 4) {
      float4 v = reinterpret_cast<const float4*>(x)[i];
      union { _Float16 h[4]; uint2 u; } a;
      a.h[0] = (_Float16)v.x;
      a.h[1] = (_Float16)v.y;
      a.h[2] = (_Float16)v.z;
      a.h[3] = (_Float16)v.w;
      reinterpret_cast<uint2*>(x1)[i] = a.u;
      reinterpret_cast<unsigned*>(x8)[i] = f32x4_to_fp8x4(v.x, v.y, v.z, v.w);
    }
  } else {
    int tid = (bid - NZ_BLOCKS - NX_BLOCKS) * 256 + threadIdx.x;  // 0..16383
    int l = tid & 63;
    int f = (tid >> 6) & 7;
    int t = (tid >> 9) & 3;
    int m = (tid >> 11) & 1;  // 0 = ws, 1 = wn
    int layer = tid >> 12;
    const float* srcs[8] = {ws0, wn0, ws1, wn1, ws2, wn2, ws3, wn3};
    const float* src = srcs[layer * 2 + m];
    _Float16* dstp =
        wp + (size_t)layer * WP_LAYER + ((((m * 4 + t) * 8 + f) * 64 + l) * 8);
    int k0 = t * 32 + (l >> 4) * 8;
    int col = f * 16 + (l & 15);
#pragma unroll
    for (int j = 0; j < 8; ++j) dstp[j] = (_Float16)src[(k0 + j) * DIM + col];
  }
}

// ---------------- aggregation v3: fp8 gather, 2 edges per instruction ----------------
// Wave = 1 node. fp8 row = 128B = 32 u32. Subgroup g = lane>>5 handles edge
// e+8g+j; lane's d = lane&31 picks u32 of the row -> each 4B/lane instruction
// covers TWO edges (full 256B/instr; r16 showed sub-dword loads don't scale).
// 8 loads in flight = 16 edges/iter. Remainder handled by a fully PREDICATED
// batch (clamped index, zeroed word) so low-degree nodes also run at 8 loads
// in flight. One shfl_xor(32) merges subgroups; lanes 0-31 write m1 coalesced.

__global__ void k_agg_fp8(const unsigned char* __restrict__ h8,
                          const int* __restrict__ offs, const int* __restrict__ esrc,
                          const float* __restrict__ deg_inv, _Float16* __restrict__ m1) {
  int wid = (blockIdx.x * blockDim.x + threadIdx.x) >> 6;  // node id
  int lane = threadIdx.x & 63;
  if (wid >= N_NODES) return;
  const unsigned* H = reinterpret_cast<const unsigned*>(h8);  // row = 32 u32
  const int g = lane >> 5;  // edge subgroup 0..1
  const int d = lane & 31;  // u32 within row
  int beg = offs[wid], end = offs[wid + 1];
  float4 accA = {0.f, 0.f, 0.f, 0.f}, accB = {0.f, 0.f, 0.f, 0.f};
  for (int e = beg; e < end; e += 16) {
    const int cnt = end - e;  // >=1
    int s[8];
#pragma unroll
    for (int j = 0; j < 8; ++j) {
      int idx = e + 8 * g + j;
      s[j] = esrc[min(idx, end - 1)];
    }
    unsigned w[8];
#pragma unroll
    for (int j = 0; j < 8; ++j) w[j] = H[(size_t)s[j] * 32 + d];
#pragma unroll
    for (int j = 0; j < 8; ++j) {
      unsigned wv = (8 * g + j < cnt) ? w[j] : 0u;  // fp8 0x00 == 0.0
      f32x2 lo = fp8x2_lo(wv);
      f32x2 hi = fp8x2_hi(wv);
      if (j & 1) {
        accB.x += lo[0]; accB.y += lo[1]; accB.z += hi[0]; accB.w += hi[1];
      } else {
        accA.x += lo[0]; accA.y += lo[1]; accA.z += hi[0]; accA.w += hi[1];
      }
    }
  }
  float4 a;
  a.x = accA.x + accB.x;
  a.y = accA.y + accB.y;
  a.z = accA.z + accB.z;
  a.w = accA.w + accB.w;
  a.x += __shfl_xor(a.x, 32);
  a.y += __shfl_xor(a.y, 32);
  a.z += __shfl_xor(a.z, 32);
  a.w += __shfl_xor(a.w, 32);
  if (lane < 32) {
    float di = deg_inv[wid];
    union { uint2 u; _Float16 h[4]; } o;
    o.h[0] = (_Float16)(a.x * di);
    o.h[1] = (_Float16)(a.y * di);
    o.h[2] = (_Float16)(a.z * di);
    o.h[3] = (_Float16)(a.w * di);
    reinterpret_cast<uint2*>(m1)[(size_t)wid * 32 + d] = o.u;
  }
}

// ---------------- MFMA dual-GEMM v8: single-plane f16, 2 MFMAs/frag ----------------
// out = act(h@ws + mean@wn + b); h = h1 (f16), mean = m1 (f16).
// acc += h1*ws_hi + m*wn_hi   (2 MFMAs per frag)
// Epilogue (l<3) writes o1 f16 (next GEMM self input) AND o8 fp8 (next agg
// gather table). h1 full-K staged upfront (16 KB LDS, 6 blk/CU), ONE barrier,
// barrier-free t-loop; mean A-frags direct from global. XOR swizzle
// chunk^=(row&7) on the GLOBAL source; reads use the same XOR.

template <int RELU, int LAST>
__global__ __launch_bounds__(256, 6) void k_gemm_f16(
    const _Float16* __restrict__ hp1, const _Float16* __restrict__ mp1,
    const _Float16* __restrict__ wp, const float* __restrict__ bias,
    float* __restrict__ outf, _Float16* __restrict__ o1,
    unsigned char* __restrict__ o8) {
  __shared__ _Float16 sA[64 * 128];  // 16 KB: [row*128 + k], swizzled

  const int tid = threadIdx.x;
  const int lane = tid & 63;
  const int wv = tid >> 6;
  const int wr = wv >> 1;  // rows wr*32..wr*32+31
  const int wc = wv & 1;   // cols wc*64..wc*64+63
  const int row0 = blockIdx.x * 64;
  const int lr = lane & 15;
  const int lg = lane >> 4;

  // ---- stage h1 full K (1024 slots of 16B) ----
#pragma unroll
  for (int i = 0; i < 4; ++i) {
    int s = i * 256 + tid;             // slot 0..1023
    int row = s >> 4;                  // 0..63
    int chunk = (s & 15) ^ (row & 7);  // swizzle on global side
    const _Float16* g = hp1 + (size_t)(row0 + row) * DIM + chunk * 8;
    _Float16* l = &sA[(size_t)(i * 256 + (tid & ~63)) * 8];
    stage16(g, l);
  }
  __syncthreads();  // single drain; loop below is barrier-free

  f32x4 acc[2][4];
#pragma unroll
  for (int i = 0; i < 2; ++i)
#pragma unroll
    for (int j = 0; j < 4; ++j) acc[i][j] = (f32x4){0.f, 0.f, 0.f, 0.f};

  const _Float16* WS1 = wp;           // ws hi
  const _Float16* WN1 = wp + WP_MAT;  // wn hi

#pragma unroll
  for (int t = 0; t < 4; ++t) {
    // mean A-frags direct from global (issued first; overlap with LDS reads + B)
    f16x8 am[2];
#pragma unroll
    for (int ri = 0; ri < 2; ++ri) {
      int row = row0 + wr * 32 + ri * 16 + lr;
      am[ri] = *reinterpret_cast<const f16x8*>(mp1 + (size_t)row * DIM + t * 32 + lg * 8);
    }
    // h A-frags from LDS (swizzled read; conflict-free)
    f16x8 a1[2];
#pragma unroll
    for (int ri = 0; ri < 2; ++ri) {
      int row_l = wr * 32 + ri * 16 + lr;
      int boff = (row_l << 8) + ((t * 64 + lg * 16) ^ ((row_l & 7) << 4));
      a1[ri] = *reinterpret_cast<const f16x8*>(
          reinterpret_cast<const char*>(&sA[0]) + boff);
    }
    // B frags from global (L2) + MFMA
#pragma unroll
    for (int fc = 0; fc < 4; ++fc) {
      int f = wc * 4 + fc;
      size_t boff = (size_t)((t * 8 + f) * 64 + lane) * 8;
      f16x8 bs1 = *reinterpret_cast<const f16x8*>(WS1 + boff);
      f16x8 bn1 = *reinterpret_cast<const f16x8*>(WN1 + boff);
#pragma unroll
      for (int ri = 0; ri < 2; ++ri) {
        acc[ri][fc] =
            __builtin_amdgcn_mfma_f32_16x16x32_f16(a1[ri], bs1, acc[ri][fc], 0, 0, 0);
        acc[ri][fc] =
            __builtin_amdgcn_mfma_f32_16x16x32_f16(am[ri], bn1, acc[ri][fc], 0, 0, 0);
      }
    }
  }

  // ---- epilogue: C/D layout col=lane&15, row=(lane>>4)*4+reg ----
  float bv[4];
#pragma unroll
  for (int fc = 0; fc < 4; ++fc) bv[fc] = bias[wc * 64 + fc * 16 + lr];
#pragma unroll
  for (int ri = 0; ri < 2; ++ri)
#pragma unroll
    for (int fc = 0; fc < 4; ++fc)
#pragma unroll
      for (int r = 0; r < 4; ++r) {
        int row = row0 + wr * 32 + ri * 16 + lg * 4 + r;
        if (row < N_NODES) {
          float v = acc[ri][fc][r] + bv[fc];
          if (RELU) v = fmaxf(v, 0.f);
          size_t idx = (size_t)row * DIM + wc * 64 + fc * 16 + lr;
          if (LAST) {
            outf[idx] = v;
          } else {
            o1[idx] = (_Float16)v;
            o8[idx] = f32_to_fp8(v);
          }
        }
      }
}

// ---------------- driver ----------------

extern "C" void kernel_launch(void* const* d_in, const int* in_sizes, int n_in,
                              void* d_out, int out_size, void* d_ws, size_t ws_size,
                              hipStream_t stream) {
  const float* x = (const float*)d_in[0];
  const int* src = (const int*)d_in[1];
  const int* dst = (const int*)d_in[2];
  const float* Ws[4];
  const float* Wn[4];
  const float* Bi[4];
  for (int i = 0; i < 4; ++i) {
    Ws[i] = (const float*)d_in[3 + 3 * i];
    Wn[i] = (const float*)d_in[4 + 3 * i];
    Bi[i] = (const float*)d_in[5 + 3 * i];
  }
  float* out = (float*)d_out;

  char* p = (char*)d_ws;
  auto take = [&](size_t bytes) {
    void* r = (void*)p;
    p += (bytes + 255) & ~(size_t)255;
    return r;
  };
  int* cnt = (int*)take((size_t)N_NODES * 4);
  int* offs = (int*)take((size_t)(N_NODES + 1) * 4);
  int* cursor = (int*)take((size_t)N_NODES * 4);
  int* partials = (int*)take(128 * 4);
  float* deg_inv = (float*)take((size_t)N_NODES * 4);
  int* esrc = (int*)take((size_t)N_EDGES * 4);
  _Float16* hA1 = (_Float16*)take((size_t)N_NODES * DIM * 2);
  _Float16* hB1 = (_Float16*)take((size_t)N_NODES * DIM * 2);
  unsigned char* h8A = (unsigned char*)take((size_t)N_NODES * DIM);
  unsigned char* h8B = (unsigned char*)take((size_t)N_NODES * DIM);
  _Float16* m1 = (_Float16*)take((size_t)N_NODES * DIM * 2);
  _Float16* wpk = (_Float16*)take((size_t)4 * WP_LAYER * 2);
  // pad so last-block OOB staging/mean reads stay inside the workspace
  (void)take((size_t)64 * 1024);

  const int NB = (N_NODES + 1023) / 1024;  // 98

  // fused preprocessing (cnt zero | x->f16+fp8 | weight pack), then CSR build
  k_preproc<<<NZ_BLOCKS + NX_BLOCKS + NW_BLOCKS, 256, 0, stream>>>(
      cnt, x, hA1, h8A, Ws[0], Wn[0], Ws[1], Wn[1], Ws[2], Wn[2], Ws[3], Wn[3], wpk);
  k_count<<<(N_EDGES + 255) / 256, 256, 0, stream>>>(dst, cnt);
  k_scan_blk<<<NB, 1024, 0, stream>>>(cnt, offs, partials);
  k_scan_part<<<1, 128, 0, stream>>>(partials, NB);
  k_scan_add<<<(N_NODES + 255) / 256, 256, 0, stream>>>(offs, partials, cnt, cursor,
                                                        deg_inv);
  k_fill8<<<8 * FILL_BPP, 256, 0, stream>>>(src, dst, cursor, esrc);

  const int AGG_BLOCKS = (N_NODES + 3) / 4;     // 4 waves/block, 1 node/wave
  const int GEMM_BLOCKS = (N_NODES + 63) / 64;  // 64 rows x 128 cols per block

  _Float16 *h1 = hA1, *n1 = hB1;
  unsigned char *h8 = h8A, *n8 = h8B;
  for (int l = 0; l < 4; ++l) {
    k_agg_fp8<<<AGG_BLOCKS, 256, 0, stream>>>(h8, offs, esrc, deg_inv, m1);
    const _Float16* wl = wpk + (size_t)l * WP_LAYER;
    if (l < 3) {
      k_gemm_f16<1, 0><<<GEMM_BLOCKS, 256, 0, stream>>>(h1, m1, wl, Bi[l], nullptr, n1,
                                                        n8);
      _Float16* t1 = h1; h1 = n1; n1 = t1;
      unsigned char* t8 = h8; h8 = n8; n8 = t8;
    } else {
      k_gemm_f16<0, 1><<<GEMM_BLOCKS, 256, 0, stream>>>(h1, m1, wl, Bi[l], out, nullptr,
                                                        nullptr);
    }
  }
}